// Round 15
// baseline (283.249 us; speedup 1.0000x reference)
//
#include <hip/hip_runtime.h>
#include <hip/hip_bf16.h>
#include <math.h>

// Problem constants: S=8192, B=4, C=512, H=8, D=64
#define S_LEN 8192
#define BATCH 4
#define CDIM  512
#define HEADS 8
#define DDIM  64
#define MROWS (S_LEN * BATCH)   // 32768 rows; row m = s*BATCH + b; layout [S,B,C]
#define EPS_F 1e-6f

typedef __attribute__((ext_vector_type(8))) short     short8_t;
typedef __attribute__((ext_vector_type(4))) float     f32x4;
typedef unsigned short ushort_t;
typedef __attribute__((ext_vector_type(8))) unsigned short ushort8_t;

static __device__ __forceinline__ ushort_t f2bf(float f) {
  __hip_bfloat16 h = __float2bfloat16(f);   // RNE
  return *(ushort_t*)&h;
}

// Async global->LDS, 16B per lane. LDS dest = wave-uniform base + lane*16.
static __device__ __forceinline__ void gl2lds16(const ushort_t* g, ushort_t* l) {
  __builtin_amdgcn_global_load_lds((const __attribute__((address_space(1))) void*)g,
                                   (__attribute__((address_space(3))) void*)l,
                                   16, 0, 0);
}

// Counted waits (T4): wait until <=N vmem ops outstanding; in-order retirement
// means everything older than the newest N is then complete.
#define WAIT_VM(N) asm volatile("s_waitcnt vmcnt(" #N ") lgkmcnt(0)" ::: "memory")

// ---------------------------------------------------------------------------
// Weights fp32 -> bf16, packed FRAGMENT-MAJOR (r9-verified):
//   frag (nfg 0..31, kfg 0..15): 64 lanes x 8 shorts contiguous (1 KB).
// ---------------------------------------------------------------------------
__global__ __launch_bounds__(256)
void cvtW_pack(const float* __restrict__ a, const float* __restrict__ b,
               const float* __restrict__ c, const float* __restrict__ d,
               ushort_t* __restrict__ oa, ushort_t* __restrict__ ob,
               ushort_t* __restrict__ oc, ushort_t* __restrict__ od) {
  const float* src = (blockIdx.y == 0) ? a : (blockIdx.y == 1) ? b :
                     (blockIdx.y == 2) ? c : d;
  ushort_t* dst    = (blockIdx.y == 0) ? oa : (blockIdx.y == 1) ? ob :
                     (blockIdx.y == 2) ? oc : od;
  const size_t i = ((size_t)blockIdx.x * 256 + threadIdx.x) * 8;
  const int n  = (int)(i >> 9);
  const int k0 = (int)(i & 511);
  const float4 x = *(const float4*)&src[i];
  const float4 y = *(const float4*)&src[i + 4];
  ushort8_t p;
  p[0] = f2bf(x.x); p[1] = f2bf(x.y); p[2] = f2bf(x.z); p[3] = f2bf(x.w);
  p[4] = f2bf(y.x); p[5] = f2bf(y.y); p[6] = f2bf(y.z); p[7] = f2bf(y.w);
  const int kf   = k0 >> 5;
  const int lane = ((k0 >> 3) & 3) * 16 + (n & 15);
  const int nfg  = n >> 4;
  *(ushort8_t*)&dst[(((size_t)nfg * 16 + kf) * 64 + lane) * 8] = p;
}

// ---------------------------------------------------------------------------
// 128x128-tile MFMA GEMM, counted-vmcnt dbuf, SMALL footprint for 3 blocks/CU:
//   Y[m][n] = act( sum_k A[m][k]*W[n][k] + bias[n] ),  K = N = 512.
// 256 thr = 4 waves (2m x 2n); wave = 64x64 = 4mf x 4nf (64 AGPR acc);
// BK=32 -> 16 K-steps. LDS 32KB total: A0,A1,B0,B1 @ 8KB (8 frags x 1KB).
// Per step: stage tile ks+1 (A: reg-cvt from loads issued 2 steps ago;
// B: packed-weight DMA) -> counted WAIT -> s_barrier -> 16 MFMA -> s_barrier.
// ---------------------------------------------------------------------------
template<int AF32, int OUTF32>
static __device__ __forceinline__
void gemm128_body(const void* __restrict__ Av, const ushort_t* __restrict__ Wpk,
                  const float* __restrict__ bias, void* __restrict__ Yv,
                  const bool act, const int m0, const int n0, ushort_t* lds) {
  const int t    = threadIdx.x;        // 0..255
  const int w    = t >> 6;             // 0..3
  const int lane = t & 63;
  const int lr   = lane & 15;
  const int lk8  = (lane >> 4) * 8;
  const int wm   = (w >> 1) * 64;      // wave m-offset
  const int wn   = (w & 1) * 64;       // wave n-offset

  const float*    Xf = (const float*)Av;
  const ushort_t* Ah = (const ushort_t*)Av;

  ushort_t* Ab[2] = { lds,        lds + 4096 };
  ushort_t* Bb[2] = { lds + 8192, lds + 12288 };

  f32x4 ar[2][2][2];   // 2 sets x 2 frags x 2 f32x4 (literal-indexed)

  auto regloadA = [&](int set, int kt) {
    #pragma unroll
    for (int j = 0; j < 2; ++j) {
      const int fid = w * 2 + j;     // 0..7
      const size_t g = (size_t)(m0 + fid * 16 + lr) * CDIM + kt + lk8;
      if (set == 0) {
        ar[0][j][0] = __builtin_nontemporal_load((const f32x4*)&Xf[g]);
        ar[0][j][1] = __builtin_nontemporal_load((const f32x4*)&Xf[g + 4]);
      } else {
        ar[1][j][0] = __builtin_nontemporal_load((const f32x4*)&Xf[g]);
        ar[1][j][1] = __builtin_nontemporal_load((const f32x4*)&Xf[g + 4]);
      }
    }
  };
  auto stageA_f32 = [&](int set, ushort_t* A_) {
    #pragma unroll
    for (int j = 0; j < 2; ++j) {
      const int fid = w * 2 + j;
      const f32x4 x0 = set ? ar[1][j][0] : ar[0][j][0];
      const f32x4 x1 = set ? ar[1][j][1] : ar[0][j][1];
      short8_t v;
      v[0] = (short)f2bf(x0[0]); v[1] = (short)f2bf(x0[1]);
      v[2] = (short)f2bf(x0[2]); v[3] = (short)f2bf(x0[3]);
      v[4] = (short)f2bf(x1[0]); v[5] = (short)f2bf(x1[1]);
      v[6] = (short)f2bf(x1[2]); v[7] = (short)f2bf(x1[3]);
      *(short8_t*)&A_[(size_t)fid * 512 + lane * 8] = v;
    }
  };
  auto stageA_bf16 = [&](ushort_t* A_, int kt) {
    #pragma unroll
    for (int j = 0; j < 2; ++j) {
      const int fid = w * 2 + j;
      const ushort_t* g = Ah + (size_t)(m0 + fid * 16 + lr) * CDIM + kt + lk8;
      gl2lds16(g, &A_[fid * 512]);
    }
  };
  auto stageB = [&](ushort_t* B_, int kt) {
    #pragma unroll
    for (int j = 0; j < 2; ++j) {
      const int fid = w * 2 + j;
      const size_t idx = (size_t)((n0 >> 4) + fid) * 16 + (kt >> 5);
      gl2lds16(Wpk + idx * 512 + lane * 8, &B_[fid * 512]);
    }
  };

  f32x4 acc[4][4];
  #pragma unroll
  for (int mf = 0; mf < 4; ++mf)
    #pragma unroll
    for (int nf = 0; nf < 4; ++nf)
      acc[mf][nf] = (f32x4){0.f, 0.f, 0.f, 0.f};

  auto compute = [&](const ushort_t* A_, const ushort_t* B_) {
    short8_t afr[4], bfr[4];
    #pragma unroll
    for (int nf = 0; nf < 4; ++nf)
      bfr[nf] = *(const short8_t*)&B_[((wn >> 4) + nf) * 512 + lane * 8];
    #pragma unroll
    for (int mf = 0; mf < 4; ++mf)
      afr[mf] = *(const short8_t*)&A_[((wm >> 4) + mf) * 512 + lane * 8];
    __builtin_amdgcn_s_setprio(1);
    #pragma unroll
    for (int mf = 0; mf < 4; ++mf)
      #pragma unroll
      for (int nf = 0; nf < 4; ++nf)
        acc[mf][nf] = __builtin_amdgcn_mfma_f32_16x16x32_bf16(
            afr[mf], bfr[nf], acc[mf][nf], 0, 0, 0);
    __builtin_amdgcn_s_setprio(0);
  };

  // ---- prologue ----
  if (AF32) {
    regloadA(0, 0);            // tile0 -> set0
    stageA_f32(0, Ab[0]);      // compiler waits set0 loads, ds_writes
    stageB(Bb[0], 0);          // 2 DMA
    regloadA(1, 32);           // tile1 -> set1
    regloadA(0, 64);           // tile2 -> set0
  } else {
    stageA_bf16(Ab[0], 0);     // 2 DMA
    stageB(Bb[0], 0);          // 2 DMA
  }
  __builtin_amdgcn_sched_barrier(0);

  // ---- 16 K-steps ----
#define KSTEP(ks, WN)                                                      \
  do {                                                                     \
    if ((ks) <= 14) {                                                      \
      if (AF32) {                                                          \
        stageA_f32(((ks) + 1) & 1, Ab[((ks) + 1) & 1]);                    \
        stageB(Bb[((ks) + 1) & 1], ((ks) + 1) * 32);                       \
        if ((ks) <= 12) regloadA(((ks) + 1) & 1, ((ks) + 3) * 32);         \
      } else {                                                             \
        stageA_bf16(Ab[((ks) + 1) & 1], ((ks) + 1) * 32);                  \
        stageB(Bb[((ks) + 1) & 1], ((ks) + 1) * 32);                       \
      }                                                                    \
    }                                                                      \
    __builtin_amdgcn_sched_barrier(0);                                     \
    WAIT_VM(WN);                                                           \
    __builtin_amdgcn_s_barrier();                                          \
    __builtin_amdgcn_sched_barrier(0);                                     \
    compute(Ab[(ks) & 1], Bb[(ks) & 1]);                                   \
    __builtin_amdgcn_s_barrier();                                          \
  } while (0)

  if (AF32) {
    // last needed op = 2nd B-DMA of step ks-1; newer ops:
    // regload(ks-1)=4 (ks-1<=12) + this step's {B 2, regload 4 (ks<=12)}
    KSTEP(0, 10);  KSTEP(1, 10);  KSTEP(2, 10);  KSTEP(3, 10);
    KSTEP(4, 10);  KSTEP(5, 10);  KSTEP(6, 10);  KSTEP(7, 10);
    KSTEP(8, 10);  KSTEP(9, 10);  KSTEP(10, 10); KSTEP(11, 10);
    KSTEP(12, 10); KSTEP(13, 6);  KSTEP(14, 2);  KSTEP(15, 0);
  } else {
    // last needed = 2nd B-DMA of step ks-1; newer = this step's 4 DMA
    KSTEP(0, 4);  KSTEP(1, 4);  KSTEP(2, 4);  KSTEP(3, 4);
    KSTEP(4, 4);  KSTEP(5, 4);  KSTEP(6, 4);  KSTEP(7, 4);
    KSTEP(8, 4);  KSTEP(9, 4);  KSTEP(10, 4); KSTEP(11, 4);
    KSTEP(12, 4); KSTEP(13, 4); KSTEP(14, 4); KSTEP(15, 0);
  }
#undef KSTEP

  // ---- epilogue ----
  if (OUTF32) {
    float* Yf = (float*)Yv;
    #pragma unroll
    for (int nf = 0; nf < 4; ++nf) {
      const int col = n0 + wn + nf * 16 + lr;
      const float bi = bias[col];
      #pragma unroll
      for (int mf = 0; mf < 4; ++mf) {
        #pragma unroll
        for (int r = 0; r < 4; ++r) {
          const int m = m0 + wm + mf * 16 + (lane >> 4) * 4 + r;
          __builtin_nontemporal_store(acc[mf][nf][r] + bi,
                                      &Yf[(size_t)m * CDIM + col]);
        }
      }
    }
  } else {
    // acc -> LDS [128][128] bf16 (exactly the 32KB), then coalesced nt stores
    ushort_t* Yh = (ushort_t*)Yv;
    #pragma unroll
    for (int nf = 0; nf < 4; ++nf) {
      const int col = wn + nf * 16 + lr;
      const float bi = bias[n0 + col];
      #pragma unroll
      for (int mf = 0; mf < 4; ++mf) {
        #pragma unroll
        for (int r = 0; r < 4; ++r) {
          const int row = wm + mf * 16 + (lane >> 4) * 4 + r;
          float vv = acc[mf][nf][r] + bi;
          if (act) vv = (vv > 0.f) ? (vv + 1.f) : expf(vv);
          lds[row * 128 + col] = f2bf(vv);
        }
      }
    }
    __syncthreads();
    #pragma unroll
    for (int it = 0; it < 8; ++it) {
      const int u   = it * 256 + t;      // 16B packet, 0..2047
      const int row = u >> 4;
      const int c8  = (u & 15) * 8;
      const short8_t v = *(const short8_t*)&lds[u * 8];
      __builtin_nontemporal_store(
          v, (short8_t*)&Yh[(size_t)(m0 + row) * CDIM + n0 + c8]);
    }
  }
}

// Q/K/V projections fused: blockIdx = (m-tile, n-tile, z)
__global__ __launch_bounds__(256)
void proj3_128(const float* __restrict__ Xq, const float* __restrict__ Xk,
               const float* __restrict__ Xv,
               const ushort_t* __restrict__ Wqp, const ushort_t* __restrict__ Wkp,
               const ushort_t* __restrict__ Wvp,
               const float* __restrict__ bq, const float* __restrict__ bk,
               const float* __restrict__ bv,
               ushort_t* __restrict__ Yq, ushort_t* __restrict__ Yk,
               ushort_t* __restrict__ Yv) {
  __shared__ __align__(16) ushort_t lds[16384];   // 32 KB
  const int z = blockIdx.z;
  const float*    X    = (z == 0) ? Xq : (z == 1) ? Xk : Xv;
  const ushort_t* Wpk  = (z == 0) ? Wqp : (z == 1) ? Wkp : Wvp;
  const float*    bias = (z == 0) ? bq : (z == 1) ? bk : bv;
  ushort_t*       Y    = (z == 0) ? Yq : (z == 1) ? Yk : Yv;
  gemm128_body<1, 0>(X, Wpk, bias, Y, z < 2,
                     blockIdx.x * 128, blockIdx.y * 128, lds);
}

// Output projection: bf16 A (DMA), fp32 out
__global__ __launch_bounds__(256)
void outp_128(const ushort_t* __restrict__ A, const ushort_t* __restrict__ Wpk,
              const float* __restrict__ bias, float* __restrict__ Y) {
  __shared__ __align__(16) ushort_t lds[16384];
  gemm128_body<0, 1>(A, Wpk, bias, Y, false,
                     blockIdx.x * 128, blockIdx.y * 128, lds);
}

// ---------------------------------------------------------------------------
// kv GEMM (verified): per (b,h), kv[d][f] = sum_s k[s][d]*v[s][f], ksum via
// ones-MFMA. Split-K grid (32 bh, 16 chunks).
// ---------------------------------------------------------------------------
__global__ __launch_bounds__(256)
void gemm_kv(const ushort_t* __restrict__ Kb, const ushort_t* __restrict__ Vb,
             float* __restrict__ kvpart, float* __restrict__ ksumpart) {
  __shared__ __align__(16) ushort_t klds[8192];
  __shared__ __align__(16) ushort_t vlds[8192];
  const int bh    = blockIdx.x;
  const int chunk = blockIdx.y;
  const int b = bh >> 3, h = bh & 7;
  const int t = threadIdx.x;
  const int w = t >> 6;
  const int lane = t & 63;

  f32x4 acc[4];
  #pragma unroll
  for (int fg = 0; fg < 4; ++fg) acc[fg] = (f32x4){0.f, 0.f, 0.f, 0.f};
  f32x4 accs = (f32x4){0.f, 0.f, 0.f, 0.f};

  short8_t ones;
  #pragma unroll
  for (int i = 0; i < 8; ++i) ones[i] = (short)0x3F80;

  for (int round = 0; round < 4; ++round) {
    const int sbase = chunk * 512 + round * 128;
    __syncthreads();
    #pragma unroll
    for (int i = 0; i < 4; ++i) {
      const int idx  = i * 256 + t;
      const int sl   = idx >> 3;
      const int d8   = idx & 7;
      const size_t src = (size_t)((sbase + sl) * BATCH + b) * CDIM + h * DDIM + d8 * 8;
      const ushort8_t kp = *(const ushort8_t*)&Kb[src];
      const ushort8_t vp = *(const ushort8_t*)&Vb[src];
      const int sb  = sl >> 5;
      const int j   = sl & 7;
      const int lp0 = (d8 & 1) * 8 + ((sl >> 3) & 3) * 16;
      const int dg  = d8 >> 1;
      const int kbase = ((sb * 4 + dg) * 64 + lp0) * 8 + j;
      #pragma unroll
      for (int e = 0; e < 8; ++e) {
        klds[kbase + e * 8] = kp[e];
        vlds[kbase + e * 8] = vp[e];
      }
    }
    __syncthreads();
    #pragma unroll
    for (int sb = 0; sb < 4; ++sb) {
      const short8_t af = *(const short8_t*)&klds[((sb * 4 + w) * 64 + lane) * 8];
      accs = __builtin_amdgcn_mfma_f32_16x16x32_bf16(af, ones, accs, 0, 0, 0);
      #pragma unroll
      for (int fg = 0; fg < 4; ++fg) {
        const short8_t bf = *(const short8_t*)&vlds[((sb * 4 + fg) * 64 + lane) * 8];
        acc[fg] = __builtin_amdgcn_mfma_f32_16x16x32_bf16(af, bf, acc[fg], 0, 0, 0);
      }
    }
  }

  const size_t obase = ((size_t)bh * 16 + chunk) * 64;
  #pragma unroll
  for (int fg = 0; fg < 4; ++fg)
    #pragma unroll
    for (int r = 0; r < 4; ++r) {
      const int d = w * 16 + (lane >> 4) * 4 + r;
      kvpart[(obase + d) * 64 + fg * 16 + (lane & 15)] = acc[fg][r];
    }
  if ((lane & 15) == 0) {
    #pragma unroll
    for (int r = 0; r < 4; ++r)
      ksumpart[obase + w * 16 + (lane >> 4) * 4 + r] = accs[r];
  }
}

// ---------------------------------------------------------------------------
__global__ __launch_bounds__(256)
void kv_finish(const float* __restrict__ kvpart, const float* __restrict__ ksumpart,
               ushort_t* __restrict__ kvT) {
  const int bh = blockIdx.x;
  const int t  = threadIdx.x;
  for (int idx = t; idx < 4096; idx += 256) {
    const int d = idx >> 6, f = idx & 63;
    float s = 0.f;
    for (int c = 0; c < 16; ++c)
      s += kvpart[(((size_t)bh * 16 + c) * 64 + d) * 64 + f];
    kvT[((size_t)bh * 80 + f) * 64 + d] = f2bf(s);
  }
  if (t < 64) {
    float s = 0.f;
    for (int c = 0; c < 16; ++c)
      s += ksumpart[((size_t)bh * 16 + c) * 64 + t];
    kvT[((size_t)bh * 80 + 64) * 64 + t] = f2bf(s);
  }
  for (int i = t; i < 15 * 64; i += 256)
    kvT[((size_t)bh * 80 + 65) * 64 + i] = 0;
}

// ---------------------------------------------------------------------------
// qkv GEMM (verified): y = (q @ kv) / (q . ksum + eps)
// ---------------------------------------------------------------------------
__global__ __launch_bounds__(256)
void gemm_qkv(ushort_t* __restrict__ Qb, const ushort_t* __restrict__ kvT) {
  __shared__ __align__(16) ushort_t alds[8192];
  __shared__ __align__(16) ushort_t blds[5120];
  const int bh    = blockIdx.x;
  const int chunk = blockIdx.y;
  const int b = bh >> 3, h = bh & 7;
  const int t = threadIdx.x;
  const int w = t >> 6;
  const int lane = t & 63;
  const int lr = lane & 15;
  const int lk = (lane >> 4) * 8;

  #pragma unroll
  for (int i = 0; i < 4; ++i) {
    const int fidx = w * 4 + i;
    const int ks = fidx >> 3, fm = fidx & 7;
    const ushort_t* src = Qb +
        (size_t)((chunk * 128 + fm * 16 + lr) * BATCH + b) * CDIM +
        h * DDIM + ks * 32 + lk;
    gl2lds16(src, &alds[fidx * 512]);
  }
  for (int idx = w; idx < 10; idx += 4) {
    const int ks = idx / 5, fg = idx % 5;
    const ushort_t* src = kvT + (size_t)(bh * 80 + fg * 16 + lr) * 64 + ks * 32 + lk;
    gl2lds16(src, &blds[idx * 512]);
  }
  __syncthreads();

  f32x4 acc[2][5];
  #pragma unroll
  for (int mi = 0; mi < 2; ++mi)
    #pragma unroll
    for (int fg = 0; fg < 5; ++fg)
      acc[mi][fg] = (f32x4){0.f, 0.f, 0.f, 0.f};

  #pragma unroll
  for (int ks = 0; ks < 2; ++ks) {
    short8_t af[2], bf[5];
    #pragma unroll
    for (int mi = 0; mi < 2; ++mi)
      af[mi] = *(const short8_t*)&alds[(ks * 8 + w * 2 + mi) * 512 + lane * 8];
    #pragma unroll
    for (int fg = 0; fg < 5; ++fg)
      bf[fg] = *(const short8_t*)&blds[(ks * 5 + fg) * 512 + lane * 8];
    #pragma unroll
    for (int mi = 0; mi < 2; ++mi)
      #pragma unroll
      for (int fg = 0; fg < 5; ++fg)
        acc[mi][fg] = __builtin_amdgcn_mfma_f32_16x16x32_bf16(
            af[mi], bf[fg], acc[mi][fg], 0, 0, 0);
  }

  #pragma unroll
  for (int mi = 0; mi < 2; ++mi) {
    #pragma unroll
    for (int r = 0; r < 4; ++r) {
      const float dv  = __shfl(acc[mi][4][r], lane & 48);
      const float inv = 1.f / (dv + EPS_F);
      const int s = chunk * 128 + w * 32 + mi * 16 + (lane >> 4) * 4 + r;
      const size_t rowb = (size_t)(s * BATCH + b) * CDIM + h * DDIM;
      #pragma unroll
      for (int fg = 0; fg < 4; ++fg)
        Qb[rowb + fg * 16 + lr] = f2bf(acc[mi][fg][r] * inv);
    }
  }
}

// ---------------------------------------------------------------------------
extern "C" void kernel_launch(void* const* d_in, const int* in_sizes, int n_in,
                              void* d_out, int out_size, void* d_ws, size_t ws_size,
                              hipStream_t stream) {
  const float* q_in = (const float*)d_in[0];
  const float* k_in = (const float*)d_in[1];
  const float* v_in = (const float*)d_in[2];
  const float* Wq   = (const float*)d_in[3];
  const float* bq   = (const float*)d_in[4];
  const float* Wk   = (const float*)d_in[5];
  const float* bk   = (const float*)d_in[6];
  const float* Wv   = (const float*)d_in[7];
  const float* bv   = (const float*)d_in[8];
  const float* Wp   = (const float*)d_in[9];
  const float* bp   = (const float*)d_in[10];
  float* out = (float*)d_out;

  const size_t NTOK = (size_t)MROWS * CDIM;      // 16,777,216 elems
  const size_t NW   = (size_t)CDIM * CDIM;       // 262,144
  ushort_t* Wqp    = (ushort_t*)d_ws;            // fragment-packed bf16 weights
  ushort_t* Wkp    = Wqp + NW;
  ushort_t* Wvp    = Wkp + NW;
  ushort_t* Wpp    = Wvp + NW;
  ushort_t* qbuf   = Wpp + NW;
  ushort_t* kbuf   = qbuf + NTOK;
  ushort_t* vbuf   = kbuf + NTOK;
  ushort_t* kvT    = vbuf + NTOK;                           // 32*80*64
  float* kvpart    = (float*)(kvT + (size_t)32 * 80 * 64);  // 512*64*64
  float* ksumpart  = kvpart + (size_t)512 * 64 * 64;        // 512*64

  const dim3 blk(256);

  // 1) Weights fp32 -> bf16, fragment-packed
  cvtW_pack<<<dim3(128, 4), blk, 0, stream>>>(Wq, Wk, Wv, Wp,
                                              Wqp, Wkp, Wvp, Wpp);

  // 2) Q/K/V projections: 128^2-tile, small-footprint counted-vmcnt pipeline
  proj3_128<<<dim3(MROWS / 128, CDIM / 128, 3), blk, 0, stream>>>(
      q_in, k_in, v_in, Wqp, Wkp, Wvp, bq, bk, bv, qbuf, kbuf, vbuf);

  // 3) kv = sum_s k^T v (+ ksum via ones-MFMA), split-K then finish
  gemm_kv<<<dim3(32, 16), blk, 0, stream>>>(kbuf, vbuf, kvpart, ksumpart);
  kv_finish<<<dim3(32), blk, 0, stream>>>(kvpart, ksumpart, kvT);

  // 4) y = (q @ kv) / (q . ksum + eps), bf16 in place over q buffer
  gemm_qkv<<<dim3(32, 64), blk, 0, stream>>>(qbuf, kvT);

  // 5) Output projection: 128^2-tile, bf16 A via DMA -> fp32 d_out
  outp_128<<<dim3(MROWS / 128, CDIM / 128), blk, 0, stream>>>(
      qbuf, Wpp, bp, out);
}

// Round 16
// 226.198 us; speedup vs baseline: 1.2522x; 1.2522x over previous
//
#include <hip/hip_runtime.h>
#include <hip/hip_bf16.h>
#include <math.h>

// Problem constants: S=8192, B=4, C=512, H=8, D=64
#define S_LEN 8192
#define BATCH 4
#define CDIM  512
#define HEADS 8
#define DDIM  64
#define MROWS (S_LEN * BATCH)   // 32768 rows; row m = s*BATCH + b; layout [S,B,C]
#define EPS_F 1e-6f

typedef __attribute__((ext_vector_type(8))) short     short8_t;
typedef __attribute__((ext_vector_type(4))) float     f32x4;
typedef unsigned short ushort_t;
typedef __attribute__((ext_vector_type(8))) unsigned short ushort8_t;

static __device__ __forceinline__ ushort_t f2bf(float f) {
  __hip_bfloat16 h = __float2bfloat16(f);   // RNE
  return *(ushort_t*)&h;
}

// Async global->LDS, 16B per lane. LDS dest = wave-uniform base + lane*16.
static __device__ __forceinline__ void gl2lds16(const ushort_t* g, ushort_t* l) {
  __builtin_amdgcn_global_load_lds((const __attribute__((address_space(1))) void*)g,
                                   (__attribute__((address_space(3))) void*)l,
                                   16, 0, 0);
}

// Counted waits (T4): wait until <=N vmem ops outstanding; in-order retirement
// means everything older than the newest N is then complete.
#define WAIT_VM(N) asm volatile("s_waitcnt vmcnt(" #N ") lgkmcnt(0)" ::: "memory")

// ---------------------------------------------------------------------------
// Weights fp32 -> bf16, packed FRAGMENT-MAJOR (r9-verified):
//   frag (nfg 0..31, kfg 0..15): 64 lanes x 8 shorts contiguous (1 KB).
// ---------------------------------------------------------------------------
__global__ __launch_bounds__(256)
void cvtW_pack(const float* __restrict__ a, const float* __restrict__ b,
               const float* __restrict__ c, const float* __restrict__ d,
               ushort_t* __restrict__ oa, ushort_t* __restrict__ ob,
               ushort_t* __restrict__ oc, ushort_t* __restrict__ od) {
  const float* src = (blockIdx.y == 0) ? a : (blockIdx.y == 1) ? b :
                     (blockIdx.y == 2) ? c : d;
  ushort_t* dst    = (blockIdx.y == 0) ? oa : (blockIdx.y == 1) ? ob :
                     (blockIdx.y == 2) ? oc : od;
  const size_t i = ((size_t)blockIdx.x * 256 + threadIdx.x) * 8;
  const int n  = (int)(i >> 9);
  const int k0 = (int)(i & 511);
  const float4 x = *(const float4*)&src[i];
  const float4 y = *(const float4*)&src[i + 4];
  ushort8_t p;
  p[0] = f2bf(x.x); p[1] = f2bf(x.y); p[2] = f2bf(x.z); p[3] = f2bf(x.w);
  p[4] = f2bf(y.x); p[5] = f2bf(y.y); p[6] = f2bf(y.z); p[7] = f2bf(y.w);
  const int kf   = k0 >> 5;
  const int lane = ((k0 >> 3) & 3) * 16 + (n & 15);
  const int nfg  = n >> 4;
  *(ushort8_t*)&dst[(((size_t)nfg * 16 + kf) * 64 + lane) * 8] = p;
}

// ---------------------------------------------------------------------------
// 128x128-tile MFMA GEMM, counted-vmcnt dbuf, SMALL footprint (2.5+ blocks/CU):
//   Y[m][n] = act( sum_k A[m][k]*W[n][k] + bias[n] ),  K = N = 512.
// 256 thr = 4 waves (2m x 2n); wave = 64x64 = 4mf x 4nf (64 AGPR acc);
// BK=32 -> 16 K-steps. LDS 32KB: A0,A1,B0,B1 @ 8KB (8 frags x 1KB).
// A loads are CACHED (no nt): grid puts the 4 n-tiles of one m-panel in
// consecutive blocks, so A is HBM-fetched once and L2-served 3x.
// ---------------------------------------------------------------------------
template<int AF32, int OUTF32>
static __device__ __forceinline__
void gemm128_body(const void* __restrict__ Av, const ushort_t* __restrict__ Wpk,
                  const float* __restrict__ bias, void* __restrict__ Yv,
                  const bool act, const int m0, const int n0, ushort_t* lds) {
  const int t    = threadIdx.x;        // 0..255
  const int w    = t >> 6;             // 0..3
  const int lane = t & 63;
  const int lr   = lane & 15;
  const int lk8  = (lane >> 4) * 8;
  const int wm   = (w >> 1) * 64;      // wave m-offset
  const int wn   = (w & 1) * 64;       // wave n-offset

  const float*    Xf = (const float*)Av;
  const ushort_t* Ah = (const ushort_t*)Av;

  ushort_t* Ab[2] = { lds,        lds + 4096 };
  ushort_t* Bb[2] = { lds + 8192, lds + 12288 };

  f32x4 ar[2][2][2];   // 2 sets x 2 frags x 2 f32x4 (literal-indexed)

  auto regloadA = [&](int set, int kt) {
    #pragma unroll
    for (int j = 0; j < 2; ++j) {
      const int fid = w * 2 + j;     // 0..7
      const size_t g = (size_t)(m0 + fid * 16 + lr) * CDIM + kt + lk8;
      if (set == 0) {
        ar[0][j][0] = *(const f32x4*)&Xf[g];
        ar[0][j][1] = *(const f32x4*)&Xf[g + 4];
      } else {
        ar[1][j][0] = *(const f32x4*)&Xf[g];
        ar[1][j][1] = *(const f32x4*)&Xf[g + 4];
      }
    }
  };
  auto stageA_f32 = [&](int set, ushort_t* A_) {
    #pragma unroll
    for (int j = 0; j < 2; ++j) {
      const int fid = w * 2 + j;
      const f32x4 x0 = set ? ar[1][j][0] : ar[0][j][0];
      const f32x4 x1 = set ? ar[1][j][1] : ar[0][j][1];
      short8_t v;
      v[0] = (short)f2bf(x0[0]); v[1] = (short)f2bf(x0[1]);
      v[2] = (short)f2bf(x0[2]); v[3] = (short)f2bf(x0[3]);
      v[4] = (short)f2bf(x1[0]); v[5] = (short)f2bf(x1[1]);
      v[6] = (short)f2bf(x1[2]); v[7] = (short)f2bf(x1[3]);
      *(short8_t*)&A_[(size_t)fid * 512 + lane * 8] = v;
    }
  };
  auto stageA_bf16 = [&](ushort_t* A_, int kt) {
    #pragma unroll
    for (int j = 0; j < 2; ++j) {
      const int fid = w * 2 + j;
      const ushort_t* g = Ah + (size_t)(m0 + fid * 16 + lr) * CDIM + kt + lk8;
      gl2lds16(g, &A_[fid * 512]);
    }
  };
  auto stageB = [&](ushort_t* B_, int kt) {
    #pragma unroll
    for (int j = 0; j < 2; ++j) {
      const int fid = w * 2 + j;
      const size_t idx = (size_t)((n0 >> 4) + fid) * 16 + (kt >> 5);
      gl2lds16(Wpk + idx * 512 + lane * 8, &B_[fid * 512]);
    }
  };

  f32x4 acc[4][4];
  #pragma unroll
  for (int mf = 0; mf < 4; ++mf)
    #pragma unroll
    for (int nf = 0; nf < 4; ++nf)
      acc[mf][nf] = (f32x4){0.f, 0.f, 0.f, 0.f};

  auto compute = [&](const ushort_t* A_, const ushort_t* B_) {
    short8_t afr[4], bfr[4];
    #pragma unroll
    for (int nf = 0; nf < 4; ++nf)
      bfr[nf] = *(const short8_t*)&B_[((wn >> 4) + nf) * 512 + lane * 8];
    #pragma unroll
    for (int mf = 0; mf < 4; ++mf)
      afr[mf] = *(const short8_t*)&A_[((wm >> 4) + mf) * 512 + lane * 8];
    __builtin_amdgcn_s_setprio(1);
    #pragma unroll
    for (int mf = 0; mf < 4; ++mf)
      #pragma unroll
      for (int nf = 0; nf < 4; ++nf)
        acc[mf][nf] = __builtin_amdgcn_mfma_f32_16x16x32_bf16(
            afr[mf], bfr[nf], acc[mf][nf], 0, 0, 0);
    __builtin_amdgcn_s_setprio(0);
  };

  // ---- prologue ----
  if (AF32) {
    regloadA(0, 0);            // tile0 -> set0
    stageA_f32(0, Ab[0]);      // compiler waits set0 loads, ds_writes
    stageB(Bb[0], 0);          // 2 DMA
    regloadA(1, 32);           // tile1 -> set1
    regloadA(0, 64);           // tile2 -> set0
  } else {
    stageA_bf16(Ab[0], 0);     // 2 DMA
    stageB(Bb[0], 0);          // 2 DMA
  }
  __builtin_amdgcn_sched_barrier(0);

  // ---- 16 K-steps ----
#define KSTEP(ks, WN)                                                      \
  do {                                                                     \
    if ((ks) <= 14) {                                                      \
      if (AF32) {                                                          \
        stageA_f32(((ks) + 1) & 1, Ab[((ks) + 1) & 1]);                    \
        stageB(Bb[((ks) + 1) & 1], ((ks) + 1) * 32);                       \
        if ((ks) <= 12) regloadA(((ks) + 1) & 1, ((ks) + 3) * 32);         \
      } else {                                                             \
        stageA_bf16(Ab[((ks) + 1) & 1], ((ks) + 1) * 32);                  \
        stageB(Bb[((ks) + 1) & 1], ((ks) + 1) * 32);                       \
      }                                                                    \
    }                                                                      \
    __builtin_amdgcn_sched_barrier(0);                                     \
    WAIT_VM(WN);                                                           \
    __builtin_amdgcn_s_barrier();                                          \
    __builtin_amdgcn_sched_barrier(0);                                     \
    compute(Ab[(ks) & 1], Bb[(ks) & 1]);                                   \
    __builtin_amdgcn_s_barrier();                                          \
  } while (0)

  if (AF32) {
    KSTEP(0, 10);  KSTEP(1, 10);  KSTEP(2, 10);  KSTEP(3, 10);
    KSTEP(4, 10);  KSTEP(5, 10);  KSTEP(6, 10);  KSTEP(7, 10);
    KSTEP(8, 10);  KSTEP(9, 10);  KSTEP(10, 10); KSTEP(11, 10);
    KSTEP(12, 10); KSTEP(13, 6);  KSTEP(14, 2);  KSTEP(15, 0);
  } else {
    KSTEP(0, 4);  KSTEP(1, 4);  KSTEP(2, 4);  KSTEP(3, 4);
    KSTEP(4, 4);  KSTEP(5, 4);  KSTEP(6, 4);  KSTEP(7, 4);
    KSTEP(8, 4);  KSTEP(9, 4);  KSTEP(10, 4); KSTEP(11, 4);
    KSTEP(12, 4); KSTEP(13, 4); KSTEP(14, 4); KSTEP(15, 0);
  }
#undef KSTEP

  // ---- epilogue ----
  if (OUTF32) {
    float* Yf = (float*)Yv;
    #pragma unroll
    for (int nf = 0; nf < 4; ++nf) {
      const int col = n0 + wn + nf * 16 + lr;
      const float bi = bias[col];
      #pragma unroll
      for (int mf = 0; mf < 4; ++mf) {
        #pragma unroll
        for (int r = 0; r < 4; ++r) {
          const int m = m0 + wm + mf * 16 + (lane >> 4) * 4 + r;
          __builtin_nontemporal_store(acc[mf][nf][r] + bi,
                                      &Yf[(size_t)m * CDIM + col]);
        }
      }
    }
  } else {
    // acc -> LDS [128][128] bf16 (exactly the 32KB), then coalesced nt stores
    ushort_t* Yh = (ushort_t*)Yv;
    #pragma unroll
    for (int nf = 0; nf < 4; ++nf) {
      const int col = wn + nf * 16 + lr;
      const float bi = bias[n0 + col];
      #pragma unroll
      for (int mf = 0; mf < 4; ++mf) {
        #pragma unroll
        for (int r = 0; r < 4; ++r) {
          const int row = wm + mf * 16 + (lane >> 4) * 4 + r;
          float vv = acc[mf][nf][r] + bi;
          if (act) vv = (vv > 0.f) ? (vv + 1.f) : expf(vv);
          lds[row * 128 + col] = f2bf(vv);
        }
      }
    }
    __syncthreads();
    #pragma unroll
    for (int it = 0; it < 8; ++it) {
      const int u   = it * 256 + t;      // 16B packet, 0..2047
      const int row = u >> 4;
      const int c8  = (u & 15) * 8;
      const short8_t v = *(const short8_t*)&lds[u * 8];
      __builtin_nontemporal_store(
          v, (short8_t*)&Yh[(size_t)(m0 + row) * CDIM + n0 + c8]);
    }
  }
}

// Q/K/V projections fused: blockIdx = (n-tile FASTEST, m-tile, z) so the 4
// n-tiles sharing an A-panel are consecutive -> A HBM-fetched once, L2 3x.
__global__ __launch_bounds__(256)
void proj3_128(const float* __restrict__ Xq, const float* __restrict__ Xk,
               const float* __restrict__ Xv,
               const ushort_t* __restrict__ Wqp, const ushort_t* __restrict__ Wkp,
               const ushort_t* __restrict__ Wvp,
               const float* __restrict__ bq, const float* __restrict__ bk,
               const float* __restrict__ bv,
               ushort_t* __restrict__ Yq, ushort_t* __restrict__ Yk,
               ushort_t* __restrict__ Yv) {
  __shared__ __align__(16) ushort_t lds[16384];   // 32 KB
  const int z = blockIdx.z;
  const float*    X    = (z == 0) ? Xq : (z == 1) ? Xk : Xv;
  const ushort_t* Wpk  = (z == 0) ? Wqp : (z == 1) ? Wkp : Wvp;
  const float*    bias = (z == 0) ? bq : (z == 1) ? bk : bv;
  ushort_t*       Y    = (z == 0) ? Yq : (z == 1) ? Yk : Yv;
  gemm128_body<1, 0>(X, Wpk, bias, Y, z < 2,
                     blockIdx.y * 128, blockIdx.x * 128, lds);
}

// Output projection: bf16 A (DMA), fp32 out; n-tile fastest likewise.
__global__ __launch_bounds__(256)
void outp_128(const ushort_t* __restrict__ A, const ushort_t* __restrict__ Wpk,
              const float* __restrict__ bias, float* __restrict__ Y) {
  __shared__ __align__(16) ushort_t lds[16384];
  gemm128_body<0, 1>(A, Wpk, bias, Y, false,
                     blockIdx.y * 128, blockIdx.x * 128, lds);
}

// ---------------------------------------------------------------------------
// kv GEMM (verified): per (b,h), kv[d][f] = sum_s k[s][d]*v[s][f], ksum via
// ones-MFMA. Split-K grid (32 bh, 16 chunks).
// ---------------------------------------------------------------------------
__global__ __launch_bounds__(256)
void gemm_kv(const ushort_t* __restrict__ Kb, const ushort_t* __restrict__ Vb,
             float* __restrict__ kvpart, float* __restrict__ ksumpart) {
  __shared__ __align__(16) ushort_t klds[8192];
  __shared__ __align__(16) ushort_t vlds[8192];
  const int bh    = blockIdx.x;
  const int chunk = blockIdx.y;
  const int b = bh >> 3, h = bh & 7;
  const int t = threadIdx.x;
  const int w = t >> 6;
  const int lane = t & 63;

  f32x4 acc[4];
  #pragma unroll
  for (int fg = 0; fg < 4; ++fg) acc[fg] = (f32x4){0.f, 0.f, 0.f, 0.f};
  f32x4 accs = (f32x4){0.f, 0.f, 0.f, 0.f};

  short8_t ones;
  #pragma unroll
  for (int i = 0; i < 8; ++i) ones[i] = (short)0x3F80;

  for (int round = 0; round < 4; ++round) {
    const int sbase = chunk * 512 + round * 128;
    __syncthreads();
    #pragma unroll
    for (int i = 0; i < 4; ++i) {
      const int idx  = i * 256 + t;
      const int sl   = idx >> 3;
      const int d8   = idx & 7;
      const size_t src = (size_t)((sbase + sl) * BATCH + b) * CDIM + h * DDIM + d8 * 8;
      const ushort8_t kp = *(const ushort8_t*)&Kb[src];
      const ushort8_t vp = *(const ushort8_t*)&Vb[src];
      const int sb  = sl >> 5;
      const int j   = sl & 7;
      const int lp0 = (d8 & 1) * 8 + ((sl >> 3) & 3) * 16;
      const int dg  = d8 >> 1;
      const int kbase = ((sb * 4 + dg) * 64 + lp0) * 8 + j;
      #pragma unroll
      for (int e = 0; e < 8; ++e) {
        klds[kbase + e * 8] = kp[e];
        vlds[kbase + e * 8] = vp[e];
      }
    }
    __syncthreads();
    #pragma unroll
    for (int sb = 0; sb < 4; ++sb) {
      const short8_t af = *(const short8_t*)&klds[((sb * 4 + w) * 64 + lane) * 8];
      accs = __builtin_amdgcn_mfma_f32_16x16x32_bf16(af, ones, accs, 0, 0, 0);
      #pragma unroll
      for (int fg = 0; fg < 4; ++fg) {
        const short8_t bf = *(const short8_t*)&vlds[((sb * 4 + fg) * 64 + lane) * 8];
        acc[fg] = __builtin_amdgcn_mfma_f32_16x16x32_bf16(af, bf, acc[fg], 0, 0, 0);
      }
    }
  }

  const size_t obase = ((size_t)bh * 16 + chunk) * 64;
  #pragma unroll
  for (int fg = 0; fg < 4; ++fg)
    #pragma unroll
    for (int r = 0; r < 4; ++r) {
      const int d = w * 16 + (lane >> 4) * 4 + r;
      kvpart[(obase + d) * 64 + fg * 16 + (lane & 15)] = acc[fg][r];
    }
  if ((lane & 15) == 0) {
    #pragma unroll
    for (int r = 0; r < 4; ++r)
      ksumpart[obase + w * 16 + (lane >> 4) * 4 + r] = accs[r];
  }
}

// ---------------------------------------------------------------------------
__global__ __launch_bounds__(256)
void kv_finish(const float* __restrict__ kvpart, const float* __restrict__ ksumpart,
               ushort_t* __restrict__ kvT) {
  const int bh = blockIdx.x;
  const int t  = threadIdx.x;
  for (int idx = t; idx < 4096; idx += 256) {
    const int d = idx >> 6, f = idx & 63;
    float s = 0.f;
    for (int c = 0; c < 16; ++c)
      s += kvpart[(((size_t)bh * 16 + c) * 64 + d) * 64 + f];
    kvT[((size_t)bh * 80 + f) * 64 + d] = f2bf(s);
  }
  if (t < 64) {
    float s = 0.f;
    for (int c = 0; c < 16; ++c)
      s += ksumpart[((size_t)bh * 16 + c) * 64 + t];
    kvT[((size_t)bh * 80 + 64) * 64 + t] = f2bf(s);
  }
  for (int i = t; i < 15 * 64; i += 256)
    kvT[((size_t)bh * 80 + 65) * 64 + i] = 0;
}

// ---------------------------------------------------------------------------
// qkv GEMM (verified): y = (q @ kv) / (q . ksum + eps)
// ---------------------------------------------------------------------------
__global__ __launch_bounds__(256)
void gemm_qkv(ushort_t* __restrict__ Qb, const ushort_t* __restrict__ kvT) {
  __shared__ __align__(16) ushort_t alds[8192];
  __shared__ __align__(16) ushort_t blds[5120];
  const int bh    = blockIdx.x;
  const int chunk = blockIdx.y;
  const int b = bh >> 3, h = bh & 7;
  const int t = threadIdx.x;
  const int w = t >> 6;
  const int lane = t & 63;
  const int lr = lane & 15;
  const int lk = (lane >> 4) * 8;

  #pragma unroll
  for (int i = 0; i < 4; ++i) {
    const int fidx = w * 4 + i;
    const int ks = fidx >> 3, fm = fidx & 7;
    const ushort_t* src = Qb +
        (size_t)((chunk * 128 + fm * 16 + lr) * BATCH + b) * CDIM +
        h * DDIM + ks * 32 + lk;
    gl2lds16(src, &alds[fidx * 512]);
  }
  for (int idx = w; idx < 10; idx += 4) {
    const int ks = idx / 5, fg = idx % 5;
    const ushort_t* src = kvT + (size_t)(bh * 80 + fg * 16 + lr) * 64 + ks * 32 + lk;
    gl2lds16(src, &blds[idx * 512]);
  }
  __syncthreads();

  f32x4 acc[2][5];
  #pragma unroll
  for (int mi = 0; mi < 2; ++mi)
    #pragma unroll
    for (int fg = 0; fg < 5; ++fg)
      acc[mi][fg] = (f32x4){0.f, 0.f, 0.f, 0.f};

  #pragma unroll
  for (int ks = 0; ks < 2; ++ks) {
    short8_t af[2], bf[5];
    #pragma unroll
    for (int mi = 0; mi < 2; ++mi)
      af[mi] = *(const short8_t*)&alds[(ks * 8 + w * 2 + mi) * 512 + lane * 8];
    #pragma unroll
    for (int fg = 0; fg < 5; ++fg)
      bf[fg] = *(const short8_t*)&blds[(ks * 5 + fg) * 512 + lane * 8];
    #pragma unroll
    for (int mi = 0; mi < 2; ++mi)
      #pragma unroll
      for (int fg = 0; fg < 5; ++fg)
        acc[mi][fg] = __builtin_amdgcn_mfma_f32_16x16x32_bf16(
            af[mi], bf[fg], acc[mi][fg], 0, 0, 0);
  }

  #pragma unroll
  for (int mi = 0; mi < 2; ++mi) {
    #pragma unroll
    for (int r = 0; r < 4; ++r) {
      const float dv  = __shfl(acc[mi][4][r], lane & 48);
      const float inv = 1.f / (dv + EPS_F);
      const int s = chunk * 128 + w * 32 + mi * 16 + (lane >> 4) * 4 + r;
      const size_t rowb = (size_t)(s * BATCH + b) * CDIM + h * DDIM;
      #pragma unroll
      for (int fg = 0; fg < 4; ++fg)
        Qb[rowb + fg * 16 + lr] = f2bf(acc[mi][fg][r] * inv);
    }
  }
}

// ---------------------------------------------------------------------------
extern "C" void kernel_launch(void* const* d_in, const int* in_sizes, int n_in,
                              void* d_out, int out_size, void* d_ws, size_t ws_size,
                              hipStream_t stream) {
  const float* q_in = (const float*)d_in[0];
  const float* k_in = (const float*)d_in[1];
  const float* v_in = (const float*)d_in[2];
  const float* Wq   = (const float*)d_in[3];
  const float* bq   = (const float*)d_in[4];
  const float* Wk   = (const float*)d_in[5];
  const float* bk   = (const float*)d_in[6];
  const float* Wv   = (const float*)d_in[7];
  const float* bv   = (const float*)d_in[8];
  const float* Wp   = (const float*)d_in[9];
  const float* bp   = (const float*)d_in[10];
  float* out = (float*)d_out;

  const size_t NTOK = (size_t)MROWS * CDIM;      // 16,777,216 elems
  const size_t NW   = (size_t)CDIM * CDIM;       // 262,144
  ushort_t* Wqp    = (ushort_t*)d_ws;            // fragment-packed bf16 weights
  ushort_t* Wkp    = Wqp + NW;
  ushort_t* Wvp    = Wkp + NW;
  ushort_t* Wpp    = Wvp + NW;
  ushort_t* qbuf   = Wpp + NW;
  ushort_t* kbuf   = qbuf + NTOK;
  ushort_t* vbuf   = kbuf + NTOK;
  ushort_t* kvT    = vbuf + NTOK;                           // 32*80*64
  float* kvpart    = (float*)(kvT + (size_t)32 * 80 * 64);  // 512*64*64
  float* ksumpart  = kvpart + (size_t)512 * 64 * 64;        // 512*64

  const dim3 blk(256);

  // 1) Weights fp32 -> bf16, fragment-packed
  cvtW_pack<<<dim3(128, 4), blk, 0, stream>>>(Wq, Wk, Wv, Wp,
                                              Wqp, Wkp, Wvp, Wpp);

  // 2) Q/K/V projections: 128^2-tile, n-tile-fastest grid (A read once)
  proj3_128<<<dim3(CDIM / 128, MROWS / 128, 3), blk, 0, stream>>>(
      q_in, k_in, v_in, Wqp, Wkp, Wvp, bq, bk, bv, qbuf, kbuf, vbuf);

  // 3) kv = sum_s k^T v (+ ksum via ones-MFMA), split-K then finish
  gemm_kv<<<dim3(32, 16), blk, 0, stream>>>(kbuf, vbuf, kvpart, ksumpart);
  kv_finish<<<dim3(32), blk, 0, stream>>>(kvpart, ksumpart, kvT);

  // 4) y = (q @ kv) / (q . ksum + eps), bf16 in place over q buffer
  gemm_qkv<<<dim3(32, 64), blk, 0, stream>>>(qbuf, kvT);

  // 5) Output projection: 128^2-tile, bf16 A via DMA -> fp32 d_out
  outp_128<<<dim3(CDIM / 128, MROWS / 128), blk, 0, stream>>>(
      qbuf, Wpp, bp, out);
}

// Round 17
// 209.114 us; speedup vs baseline: 1.3545x; 1.0817x over previous
//
#include <hip/hip_runtime.h>
#include <hip/hip_bf16.h>
#include <math.h>

// Problem constants: S=8192, B=4, C=512, H=8, D=64
#define S_LEN 8192
#define BATCH 4
#define CDIM  512
#define HEADS 8
#define DDIM  64
#define MROWS (S_LEN * BATCH)   // 32768 rows; row m = s*BATCH + b; layout [S,B,C]
#define EPS_F 1e-6f

typedef __attribute__((ext_vector_type(8))) short     short8_t;
typedef __attribute__((ext_vector_type(4))) float     f32x4;
typedef unsigned short ushort_t;
typedef __attribute__((ext_vector_type(8))) unsigned short ushort8_t;

static __device__ __forceinline__ ushort_t f2bf(float f) {
  __hip_bfloat16 h = __float2bfloat16(f);   // RNE
  return *(ushort_t*)&h;
}

// Async global->LDS, 16B per lane. LDS dest = wave-uniform base + lane*16.
static __device__ __forceinline__ void gl2lds16(const ushort_t* g, ushort_t* l) {
  __builtin_amdgcn_global_load_lds((const __attribute__((address_space(1))) void*)g,
                                   (__attribute__((address_space(3))) void*)l,
                                   16, 0, 0);
}

// Counted waits (T4): wait until <=N vmem ops outstanding; in-order retirement
// means everything older than the newest N is then complete.
#define WAIT_VM(N) asm volatile("s_waitcnt vmcnt(" #N ") lgkmcnt(0)" ::: "memory")

// ---------------------------------------------------------------------------
// Weights fp32 -> bf16, packed FRAGMENT-MAJOR (r9-verified):
//   frag (nfg 0..31, kfg 0..15): 64 lanes x 8 shorts contiguous (1 KB).
// ---------------------------------------------------------------------------
__global__ __launch_bounds__(256)
void cvtW_pack(const float* __restrict__ a, const float* __restrict__ b,
               const float* __restrict__ c, const float* __restrict__ d,
               ushort_t* __restrict__ oa, ushort_t* __restrict__ ob,
               ushort_t* __restrict__ oc, ushort_t* __restrict__ od) {
  const float* src = (blockIdx.y == 0) ? a : (blockIdx.y == 1) ? b :
                     (blockIdx.y == 2) ? c : d;
  ushort_t* dst    = (blockIdx.y == 0) ? oa : (blockIdx.y == 1) ? ob :
                     (blockIdx.y == 2) ? oc : od;
  const size_t i = ((size_t)blockIdx.x * 256 + threadIdx.x) * 8;
  const int n  = (int)(i >> 9);
  const int k0 = (int)(i & 511);
  const float4 x = *(const float4*)&src[i];
  const float4 y = *(const float4*)&src[i + 4];
  ushort8_t p;
  p[0] = f2bf(x.x); p[1] = f2bf(x.y); p[2] = f2bf(x.z); p[3] = f2bf(x.w);
  p[4] = f2bf(y.x); p[5] = f2bf(y.y); p[6] = f2bf(y.z); p[7] = f2bf(y.w);
  const int kf   = k0 >> 5;
  const int lane = ((k0 >> 3) & 3) * 16 + (n & 15);
  const int nfg  = n >> 4;
  *(ushort8_t*)&dst[(((size_t)nfg * 16 + kf) * 64 + lane) * 8] = p;
}

// ---------------------------------------------------------------------------
// 128x128-tile MFMA GEMM, counted-vmcnt dbuf, small footprint (r16-verified).
//   Y[m][n] = act( sum_k A[m][k]*W[n][k] + bias[n] ),  K = N = 512.
// 256 thr = 4 waves (2m x 2n); wave = 64x64 = 4mf x 4nf; BK=32 -> 16 K-steps.
// LDS 32KB: A0,A1,B0,B1 @ 8KB. A loads cached; XCD swizzle (launch side)
// puts the 4 n-tiles of one m-panel on ONE XCD's L2.
// ---------------------------------------------------------------------------
template<int AF32, int OUTF32>
static __device__ __forceinline__
void gemm128_body(const void* __restrict__ Av, const ushort_t* __restrict__ Wpk,
                  const float* __restrict__ bias, void* __restrict__ Yv,
                  const bool act, const int m0, const int n0, ushort_t* lds) {
  const int t    = threadIdx.x;        // 0..255
  const int w    = t >> 6;             // 0..3
  const int lane = t & 63;
  const int lr   = lane & 15;
  const int lk8  = (lane >> 4) * 8;
  const int wm   = (w >> 1) * 64;      // wave m-offset
  const int wn   = (w & 1) * 64;       // wave n-offset

  const float*    Xf = (const float*)Av;
  const ushort_t* Ah = (const ushort_t*)Av;

  ushort_t* Ab[2] = { lds,        lds + 4096 };
  ushort_t* Bb[2] = { lds + 8192, lds + 12288 };

  f32x4 ar[2][2][2];   // 2 sets x 2 frags x 2 f32x4 (literal-indexed)

  auto regloadA = [&](int set, int kt) {
    #pragma unroll
    for (int j = 0; j < 2; ++j) {
      const int fid = w * 2 + j;     // 0..7
      const size_t g = (size_t)(m0 + fid * 16 + lr) * CDIM + kt + lk8;
      if (set == 0) {
        ar[0][j][0] = *(const f32x4*)&Xf[g];
        ar[0][j][1] = *(const f32x4*)&Xf[g + 4];
      } else {
        ar[1][j][0] = *(const f32x4*)&Xf[g];
        ar[1][j][1] = *(const f32x4*)&Xf[g + 4];
      }
    }
  };
  auto stageA_f32 = [&](int set, ushort_t* A_) {
    #pragma unroll
    for (int j = 0; j < 2; ++j) {
      const int fid = w * 2 + j;
      const f32x4 x0 = set ? ar[1][j][0] : ar[0][j][0];
      const f32x4 x1 = set ? ar[1][j][1] : ar[0][j][1];
      short8_t v;
      v[0] = (short)f2bf(x0[0]); v[1] = (short)f2bf(x0[1]);
      v[2] = (short)f2bf(x0[2]); v[3] = (short)f2bf(x0[3]);
      v[4] = (short)f2bf(x1[0]); v[5] = (short)f2bf(x1[1]);
      v[6] = (short)f2bf(x1[2]); v[7] = (short)f2bf(x1[3]);
      *(short8_t*)&A_[(size_t)fid * 512 + lane * 8] = v;
    }
  };
  auto stageA_bf16 = [&](ushort_t* A_, int kt) {
    #pragma unroll
    for (int j = 0; j < 2; ++j) {
      const int fid = w * 2 + j;
      const ushort_t* g = Ah + (size_t)(m0 + fid * 16 + lr) * CDIM + kt + lk8;
      gl2lds16(g, &A_[fid * 512]);
    }
  };
  auto stageB = [&](ushort_t* B_, int kt) {
    #pragma unroll
    for (int j = 0; j < 2; ++j) {
      const int fid = w * 2 + j;
      const size_t idx = (size_t)((n0 >> 4) + fid) * 16 + (kt >> 5);
      gl2lds16(Wpk + idx * 512 + lane * 8, &B_[fid * 512]);
    }
  };

  f32x4 acc[4][4];
  #pragma unroll
  for (int mf = 0; mf < 4; ++mf)
    #pragma unroll
    for (int nf = 0; nf < 4; ++nf)
      acc[mf][nf] = (f32x4){0.f, 0.f, 0.f, 0.f};

  auto compute = [&](const ushort_t* A_, const ushort_t* B_) {
    short8_t afr[4], bfr[4];
    #pragma unroll
    for (int nf = 0; nf < 4; ++nf)
      bfr[nf] = *(const short8_t*)&B_[((wn >> 4) + nf) * 512 + lane * 8];
    #pragma unroll
    for (int mf = 0; mf < 4; ++mf)
      afr[mf] = *(const short8_t*)&A_[((wm >> 4) + mf) * 512 + lane * 8];
    __builtin_amdgcn_s_setprio(1);
    #pragma unroll
    for (int mf = 0; mf < 4; ++mf)
      #pragma unroll
      for (int nf = 0; nf < 4; ++nf)
        acc[mf][nf] = __builtin_amdgcn_mfma_f32_16x16x32_bf16(
            afr[mf], bfr[nf], acc[mf][nf], 0, 0, 0);
    __builtin_amdgcn_s_setprio(0);
  };

  // ---- prologue ----
  if (AF32) {
    regloadA(0, 0);            // tile0 -> set0
    stageA_f32(0, Ab[0]);      // compiler waits set0 loads, ds_writes
    stageB(Bb[0], 0);          // 2 DMA
    regloadA(1, 32);           // tile1 -> set1
    regloadA(0, 64);           // tile2 -> set0
  } else {
    stageA_bf16(Ab[0], 0);     // 2 DMA
    stageB(Bb[0], 0);          // 2 DMA
  }
  __builtin_amdgcn_sched_barrier(0);

  // ---- 16 K-steps ----
#define KSTEP(ks, WN)                                                      \
  do {                                                                     \
    if ((ks) <= 14) {                                                      \
      if (AF32) {                                                          \
        stageA_f32(((ks) + 1) & 1, Ab[((ks) + 1) & 1]);                    \
        stageB(Bb[((ks) + 1) & 1], ((ks) + 1) * 32);                       \
        if ((ks) <= 12) regloadA(((ks) + 1) & 1, ((ks) + 3) * 32);         \
      } else {                                                             \
        stageA_bf16(Ab[((ks) + 1) & 1], ((ks) + 1) * 32);                  \
        stageB(Bb[((ks) + 1) & 1], ((ks) + 1) * 32);                       \
      }                                                                    \
    }                                                                      \
    __builtin_amdgcn_sched_barrier(0);                                     \
    WAIT_VM(WN);                                                           \
    __builtin_amdgcn_s_barrier();                                          \
    __builtin_amdgcn_sched_barrier(0);                                     \
    compute(Ab[(ks) & 1], Bb[(ks) & 1]);                                   \
    __builtin_amdgcn_s_barrier();                                          \
  } while (0)

  if (AF32) {
    KSTEP(0, 10);  KSTEP(1, 10);  KSTEP(2, 10);  KSTEP(3, 10);
    KSTEP(4, 10);  KSTEP(5, 10);  KSTEP(6, 10);  KSTEP(7, 10);
    KSTEP(8, 10);  KSTEP(9, 10);  KSTEP(10, 10); KSTEP(11, 10);
    KSTEP(12, 10); KSTEP(13, 6);  KSTEP(14, 2);  KSTEP(15, 0);
  } else {
    KSTEP(0, 4);  KSTEP(1, 4);  KSTEP(2, 4);  KSTEP(3, 4);
    KSTEP(4, 4);  KSTEP(5, 4);  KSTEP(6, 4);  KSTEP(7, 4);
    KSTEP(8, 4);  KSTEP(9, 4);  KSTEP(10, 4); KSTEP(11, 4);
    KSTEP(12, 4); KSTEP(13, 4); KSTEP(14, 4); KSTEP(15, 0);
  }
#undef KSTEP

  // ---- epilogue ----
  if (OUTF32) {
    float* Yf = (float*)Yv;
    #pragma unroll
    for (int nf = 0; nf < 4; ++nf) {
      const int col = n0 + wn + nf * 16 + lr;
      const float bi = bias[col];
      #pragma unroll
      for (int mf = 0; mf < 4; ++mf) {
        #pragma unroll
        for (int r = 0; r < 4; ++r) {
          const int m = m0 + wm + mf * 16 + (lane >> 4) * 4 + r;
          __builtin_nontemporal_store(acc[mf][nf][r] + bi,
                                      &Yf[(size_t)m * CDIM + col]);
        }
      }
    }
  } else {
    // acc -> LDS [128][128] bf16 (exactly the 32KB), then coalesced nt stores
    ushort_t* Yh = (ushort_t*)Yv;
    #pragma unroll
    for (int nf = 0; nf < 4; ++nf) {
      const int col = wn + nf * 16 + lr;
      const float bi = bias[n0 + col];
      #pragma unroll
      for (int mf = 0; mf < 4; ++mf) {
        #pragma unroll
        for (int r = 0; r < 4; ++r) {
          const int row = wm + mf * 16 + (lane >> 4) * 4 + r;
          float vv = acc[mf][nf][r] + bi;
          if (act) vv = (vv > 0.f) ? (vv + 1.f) : expf(vv);
          lds[row * 128 + col] = f2bf(vv);
        }
      }
    }
    __syncthreads();
    #pragma unroll
    for (int it = 0; it < 8; ++it) {
      const int u   = it * 256 + t;      // 16B packet, 0..2047
      const int row = u >> 4;
      const int c8  = (u & 15) * 8;
      const short8_t v = *(const short8_t*)&lds[u * 8];
      __builtin_nontemporal_store(
          v, (short8_t*)&Yh[(size_t)(m0 + row) * CDIM + n0 + c8]);
    }
  }
}

// Q/K/V projections fused, XCD-swizzled 1D grid (3072 blocks):
//   D -> xcd=D&7, n=(D>>3)&3, slot=D>>5, g=slot*8+xcd, m=g&255, z=g>>8.
// The 4 n-tiles of group g sit at D, D+8, D+16, D+24 -> same XCD (D%8),
// dispatched together -> A-panel HBM-fetched once, L2-served 3x.
__global__ __launch_bounds__(256)
void proj3_128(const float* __restrict__ Xq, const float* __restrict__ Xk,
               const float* __restrict__ Xv,
               const ushort_t* __restrict__ Wqp, const ushort_t* __restrict__ Wkp,
               const ushort_t* __restrict__ Wvp,
               const float* __restrict__ bq, const float* __restrict__ bk,
               const float* __restrict__ bv,
               ushort_t* __restrict__ Yq, ushort_t* __restrict__ Yk,
               ushort_t* __restrict__ Yv) {
  __shared__ __align__(16) ushort_t lds[16384];   // 32 KB
  const int D    = blockIdx.x;        // 0..3071
  const int xcd  = D & 7;
  const int n    = (D >> 3) & 3;
  const int slot = D >> 5;            // 0..95
  const int g    = slot * 8 + xcd;    // 0..767
  const int m    = g & 255;
  const int z    = g >> 8;            // 0..2
  const float*    X    = (z == 0) ? Xq : (z == 1) ? Xk : Xv;
  const ushort_t* Wpk  = (z == 0) ? Wqp : (z == 1) ? Wkp : Wvp;
  const float*    bias = (z == 0) ? bq : (z == 1) ? bk : bv;
  ushort_t*       Y    = (z == 0) ? Yq : (z == 1) ? Yk : Yv;
  gemm128_body<1, 0>(X, Wpk, bias, Y, z < 2, m * 128, n * 128, lds);
}

// Output projection: bf16 A (DMA), fp32 out; same XCD swizzle (1024 blocks):
//   xcd=D&7, n=(D>>3)&3, slot=D>>5 (0..31), m=slot*8+xcd.
__global__ __launch_bounds__(256)
void outp_128(const ushort_t* __restrict__ A, const ushort_t* __restrict__ Wpk,
              const float* __restrict__ bias, float* __restrict__ Y) {
  __shared__ __align__(16) ushort_t lds[16384];
  const int D    = blockIdx.x;        // 0..1023
  const int xcd  = D & 7;
  const int n    = (D >> 3) & 3;
  const int slot = D >> 5;            // 0..31
  const int m    = slot * 8 + xcd;    // 0..255
  gemm128_body<0, 1>(A, Wpk, bias, Y, false, m * 128, n * 128, lds);
}

// ---------------------------------------------------------------------------
// kv GEMM (verified): per (b,h), kv[d][f] = sum_s k[s][d]*v[s][f], ksum via
// ones-MFMA. Split-K grid (32 bh, 16 chunks).
// ---------------------------------------------------------------------------
__global__ __launch_bounds__(256)
void gemm_kv(const ushort_t* __restrict__ Kb, const ushort_t* __restrict__ Vb,
             float* __restrict__ kvpart, float* __restrict__ ksumpart) {
  __shared__ __align__(16) ushort_t klds[8192];
  __shared__ __align__(16) ushort_t vlds[8192];
  const int bh    = blockIdx.x;
  const int chunk = blockIdx.y;
  const int b = bh >> 3, h = bh & 7;
  const int t = threadIdx.x;
  const int w = t >> 6;
  const int lane = t & 63;

  f32x4 acc[4];
  #pragma unroll
  for (int fg = 0; fg < 4; ++fg) acc[fg] = (f32x4){0.f, 0.f, 0.f, 0.f};
  f32x4 accs = (f32x4){0.f, 0.f, 0.f, 0.f};

  short8_t ones;
  #pragma unroll
  for (int i = 0; i < 8; ++i) ones[i] = (short)0x3F80;

  for (int round = 0; round < 4; ++round) {
    const int sbase = chunk * 512 + round * 128;
    __syncthreads();
    #pragma unroll
    for (int i = 0; i < 4; ++i) {
      const int idx  = i * 256 + t;
      const int sl   = idx >> 3;
      const int d8   = idx & 7;
      const size_t src = (size_t)((sbase + sl) * BATCH + b) * CDIM + h * DDIM + d8 * 8;
      const ushort8_t kp = *(const ushort8_t*)&Kb[src];
      const ushort8_t vp = *(const ushort8_t*)&Vb[src];
      const int sb  = sl >> 5;
      const int j   = sl & 7;
      const int lp0 = (d8 & 1) * 8 + ((sl >> 3) & 3) * 16;
      const int dg  = d8 >> 1;
      const int kbase = ((sb * 4 + dg) * 64 + lp0) * 8 + j;
      #pragma unroll
      for (int e = 0; e < 8; ++e) {
        klds[kbase + e * 8] = kp[e];
        vlds[kbase + e * 8] = vp[e];
      }
    }
    __syncthreads();
    #pragma unroll
    for (int sb = 0; sb < 4; ++sb) {
      const short8_t af = *(const short8_t*)&klds[((sb * 4 + w) * 64 + lane) * 8];
      accs = __builtin_amdgcn_mfma_f32_16x16x32_bf16(af, ones, accs, 0, 0, 0);
      #pragma unroll
      for (int fg = 0; fg < 4; ++fg) {
        const short8_t bf = *(const short8_t*)&vlds[((sb * 4 + fg) * 64 + lane) * 8];
        acc[fg] = __builtin_amdgcn_mfma_f32_16x16x32_bf16(af, bf, acc[fg], 0, 0, 0);
      }
    }
  }

  const size_t obase = ((size_t)bh * 16 + chunk) * 64;
  #pragma unroll
  for (int fg = 0; fg < 4; ++fg)
    #pragma unroll
    for (int r = 0; r < 4; ++r) {
      const int d = w * 16 + (lane >> 4) * 4 + r;
      kvpart[(obase + d) * 64 + fg * 16 + (lane & 15)] = acc[fg][r];
    }
  if ((lane & 15) == 0) {
    #pragma unroll
    for (int r = 0; r < 4; ++r)
      ksumpart[obase + w * 16 + (lane >> 4) * 4 + r] = accs[r];
  }
}

// ---------------------------------------------------------------------------
__global__ __launch_bounds__(256)
void kv_finish(const float* __restrict__ kvpart, const float* __restrict__ ksumpart,
               ushort_t* __restrict__ kvT) {
  const int bh = blockIdx.x;
  const int t  = threadIdx.x;
  for (int idx = t; idx < 4096; idx += 256) {
    const int d = idx >> 6, f = idx & 63;
    float s = 0.f;
    for (int c = 0; c < 16; ++c)
      s += kvpart[(((size_t)bh * 16 + c) * 64 + d) * 64 + f];
    kvT[((size_t)bh * 80 + f) * 64 + d] = f2bf(s);
  }
  if (t < 64) {
    float s = 0.f;
    for (int c = 0; c < 16; ++c)
      s += ksumpart[((size_t)bh * 16 + c) * 64 + t];
    kvT[((size_t)bh * 80 + 64) * 64 + t] = f2bf(s);
  }
  for (int i = t; i < 15 * 64; i += 256)
    kvT[((size_t)bh * 80 + 65) * 64 + i] = 0;
}

// ---------------------------------------------------------------------------
// qkv GEMM (verified): y = (q @ kv) / (q . ksum + eps)
// ---------------------------------------------------------------------------
__global__ __launch_bounds__(256)
void gemm_qkv(ushort_t* __restrict__ Qb, const ushort_t* __restrict__ kvT) {
  __shared__ __align__(16) ushort_t alds[8192];
  __shared__ __align__(16) ushort_t blds[5120];
  const int bh    = blockIdx.x;
  const int chunk = blockIdx.y;
  const int b = bh >> 3, h = bh & 7;
  const int t = threadIdx.x;
  const int w = t >> 6;
  const int lane = t & 63;
  const int lr = lane & 15;
  const int lk = (lane >> 4) * 8;

  #pragma unroll
  for (int i = 0; i < 4; ++i) {
    const int fidx = w * 4 + i;
    const int ks = fidx >> 3, fm = fidx & 7;
    const ushort_t* src = Qb +
        (size_t)((chunk * 128 + fm * 16 + lr) * BATCH + b) * CDIM +
        h * DDIM + ks * 32 + lk;
    gl2lds16(src, &alds[fidx * 512]);
  }
  for (int idx = w; idx < 10; idx += 4) {
    const int ks = idx / 5, fg = idx % 5;
    const ushort_t* src = kvT + (size_t)(bh * 80 + fg * 16 + lr) * 64 + ks * 32 + lk;
    gl2lds16(src, &blds[idx * 512]);
  }
  __syncthreads();

  f32x4 acc[2][5];
  #pragma unroll
  for (int mi = 0; mi < 2; ++mi)
    #pragma unroll
    for (int fg = 0; fg < 5; ++fg)
      acc[mi][fg] = (f32x4){0.f, 0.f, 0.f, 0.f};

  #pragma unroll
  for (int ks = 0; ks < 2; ++ks) {
    short8_t af[2], bf[5];
    #pragma unroll
    for (int mi = 0; mi < 2; ++mi)
      af[mi] = *(const short8_t*)&alds[(ks * 8 + w * 2 + mi) * 512 + lane * 8];
    #pragma unroll
    for (int fg = 0; fg < 5; ++fg)
      bf[fg] = *(const short8_t*)&blds[(ks * 5 + fg) * 512 + lane * 8];
    #pragma unroll
    for (int mi = 0; mi < 2; ++mi)
      #pragma unroll
      for (int fg = 0; fg < 5; ++fg)
        acc[mi][fg] = __builtin_amdgcn_mfma_f32_16x16x32_bf16(
            af[mi], bf[fg], acc[mi][fg], 0, 0, 0);
  }

  #pragma unroll
  for (int mi = 0; mi < 2; ++mi) {
    #pragma unroll
    for (int r = 0; r < 4; ++r) {
      const float dv  = __shfl(acc[mi][4][r], lane & 48);
      const float inv = 1.f / (dv + EPS_F);
      const int s = chunk * 128 + w * 32 + mi * 16 + (lane >> 4) * 4 + r;
      const size_t rowb = (size_t)(s * BATCH + b) * CDIM + h * DDIM;
      #pragma unroll
      for (int fg = 0; fg < 4; ++fg)
        Qb[rowb + fg * 16 + lr] = f2bf(acc[mi][fg][r] * inv);
    }
  }
}

// ---------------------------------------------------------------------------
extern "C" void kernel_launch(void* const* d_in, const int* in_sizes, int n_in,
                              void* d_out, int out_size, void* d_ws, size_t ws_size,
                              hipStream_t stream) {
  const float* q_in = (const float*)d_in[0];
  const float* k_in = (const float*)d_in[1];
  const float* v_in = (const float*)d_in[2];
  const float* Wq   = (const float*)d_in[3];
  const float* bq   = (const float*)d_in[4];
  const float* Wk   = (const float*)d_in[5];
  const float* bk   = (const float*)d_in[6];
  const float* Wv   = (const float*)d_in[7];
  const float* bv   = (const float*)d_in[8];
  const float* Wp   = (const float*)d_in[9];
  const float* bp   = (const float*)d_in[10];
  float* out = (float*)d_out;

  const size_t NTOK = (size_t)MROWS * CDIM;      // 16,777,216 elems
  const size_t NW   = (size_t)CDIM * CDIM;       // 262,144
  ushort_t* Wqp    = (ushort_t*)d_ws;            // fragment-packed bf16 weights
  ushort_t* Wkp    = Wqp + NW;
  ushort_t* Wvp    = Wkp + NW;
  ushort_t* Wpp    = Wvp + NW;
  ushort_t* qbuf   = Wpp + NW;
  ushort_t* kbuf   = qbuf + NTOK;
  ushort_t* vbuf   = kbuf + NTOK;
  ushort_t* kvT    = vbuf + NTOK;                           // 32*80*64
  float* kvpart    = (float*)(kvT + (size_t)32 * 80 * 64);  // 512*64*64
  float* ksumpart  = kvpart + (size_t)512 * 64 * 64;        // 512*64

  const dim3 blk(256);

  // 1) Weights fp32 -> bf16, fragment-packed
  cvtW_pack<<<dim3(128, 4), blk, 0, stream>>>(Wq, Wk, Wv, Wp,
                                              Wqp, Wkp, Wvp, Wpp);

  // 2) Q/K/V projections: 128^2-tile, XCD-swizzled grid (A fetched once/XCD)
  proj3_128<<<dim3(3072), blk, 0, stream>>>(
      q_in, k_in, v_in, Wqp, Wkp, Wvp, bq, bk, bv, qbuf, kbuf, vbuf);

  // 3) kv = sum_s k^T v (+ ksum via ones-MFMA), split-K then finish
  gemm_kv<<<dim3(32, 16), blk, 0, stream>>>(kbuf, vbuf, kvpart, ksumpart);
  kv_finish<<<dim3(32), blk, 0, stream>>>(kvpart, ksumpart, kvT);

  // 4) y = (q @ kv) / (q . ksum + eps), bf16 in place over q buffer
  gemm_qkv<<<dim3(32, 64), blk, 0, stream>>>(qbuf, kvT);

  // 5) Output projection: 128^2-tile, XCD-swizzled, bf16 A -> fp32 d_out
  outp_128<<<dim3(1024), blk, 0, stream>>>(qbuf, Wpp, bp, out);
}

// Round 18
// 202.740 us; speedup vs baseline: 1.3971x; 1.0314x over previous
//
#include <hip/hip_runtime.h>
#include <hip/hip_bf16.h>
#include <math.h>

// Problem constants: S=8192, B=4, C=512, H=8, D=64
#define S_LEN 8192
#define BATCH 4
#define CDIM  512
#define HEADS 8
#define DDIM  64
#define MROWS (S_LEN * BATCH)   // 32768 rows; row m = s*BATCH + b; layout [S,B,C]
#define EPS_F 1e-6f

typedef __attribute__((ext_vector_type(8))) short     short8_t;
typedef __attribute__((ext_vector_type(4))) float     f32x4;
typedef unsigned short ushort_t;
typedef __attribute__((ext_vector_type(8))) unsigned short ushort8_t;

static __device__ __forceinline__ ushort_t f2bf(float f) {
  __hip_bfloat16 h = __float2bfloat16(f);   // RNE
  return *(ushort_t*)&h;
}

static __device__ __forceinline__ short8_t cvt8(f32x4 lo, f32x4 hi) {
  short8_t v;
  v[0] = (short)f2bf(lo[0]); v[1] = (short)f2bf(lo[1]);
  v[2] = (short)f2bf(lo[2]); v[3] = (short)f2bf(lo[3]);
  v[4] = (short)f2bf(hi[0]); v[5] = (short)f2bf(hi[1]);
  v[6] = (short)f2bf(hi[2]); v[7] = (short)f2bf(hi[3]);
  return v;
}

// Async global->LDS, 16B per lane. LDS dest = wave-uniform base + lane*16;
// global source is per-lane.
static __device__ __forceinline__ void gl2lds16(const void* g, void* l) {
  __builtin_amdgcn_global_load_lds((const __attribute__((address_space(1))) void*)g,
                                   (__attribute__((address_space(3))) void*)l,
                                   16, 0, 0);
}

// Counted waits (T4): wait until <=N vmem ops outstanding; in-order retirement
// means everything older than the newest N is then complete.
#define WAIT_VM(N) asm volatile("s_waitcnt vmcnt(" #N ") lgkmcnt(0)" ::: "memory")

// ---------------------------------------------------------------------------
// Weights fp32 -> bf16, packed FRAGMENT-MAJOR (r9-verified):
//   frag (nfg 0..31, kfg 0..15): 64 lanes x 8 shorts contiguous (1 KB).
// ---------------------------------------------------------------------------
__global__ __launch_bounds__(256)
void cvtW_pack(const float* __restrict__ a, const float* __restrict__ b,
               const float* __restrict__ c, const float* __restrict__ d,
               ushort_t* __restrict__ oa, ushort_t* __restrict__ ob,
               ushort_t* __restrict__ oc, ushort_t* __restrict__ od) {
  const float* src = (blockIdx.y == 0) ? a : (blockIdx.y == 1) ? b :
                     (blockIdx.y == 2) ? c : d;
  ushort_t* dst    = (blockIdx.y == 0) ? oa : (blockIdx.y == 1) ? ob :
                     (blockIdx.y == 2) ? oc : od;
  const size_t i = ((size_t)blockIdx.x * 256 + threadIdx.x) * 8;
  const int n  = (int)(i >> 9);
  const int k0 = (int)(i & 511);
  const float4 x = *(const float4*)&src[i];
  const float4 y = *(const float4*)&src[i + 4];
  ushort8_t p;
  p[0] = f2bf(x.x); p[1] = f2bf(x.y); p[2] = f2bf(x.z); p[3] = f2bf(x.w);
  p[4] = f2bf(y.x); p[5] = f2bf(y.y); p[6] = f2bf(y.z); p[7] = f2bf(y.w);
  const int kf   = k0 >> 5;
  const int lane = ((k0 >> 3) & 3) * 16 + (n & 15);
  const int nfg  = n >> 4;
  *(ushort8_t*)&dst[(((size_t)nfg * 16 + kf) * 64 + lane) * 8] = p;
}

// ---------------------------------------------------------------------------
// 128x128-tile MFMA GEMM, counted-vmcnt dbuf, ALL-DMA staging:
//   Y[m][n] = act( sum_k A[m][k]*W[n][k] + bias[n] ),  K = N = 512.
// 256 thr = 4 waves (2m x 2n); wave = 64x64 = 4mf x 4nf; BK=32 -> 16 K-steps.
// AF32: A staged as FP32 in LDS via global_load_lds (2 half-frag DMAs per
// frag, 4 floats/lane each); cvt fp32->bf16 AFTER ds_read, under the MFMAs.
// No register round-trip, no ds_writes -> same fire-and-forget schedule as
// the (measured ~660 TF) bf16 path. LDS: AF32 48KB, bf16 32KB.
// ---------------------------------------------------------------------------
template<int AF32, int OUTF32>
static __device__ __forceinline__
void gemm128_body(const void* __restrict__ Av, const ushort_t* __restrict__ Wpk,
                  const float* __restrict__ bias, void* __restrict__ Yv,
                  const bool act, const int m0, const int n0, ushort_t* lds) {
  const int t    = threadIdx.x;        // 0..255
  const int w    = t >> 6;             // 0..3
  const int lane = t & 63;
  const int lr   = lane & 15;
  const int lk8  = (lane >> 4) * 8;
  const int wm   = (w >> 1) * 64;      // wave m-offset
  const int wn   = (w & 1) * 64;       // wave n-offset

  const float*    Xf = (const float*)Av;
  const ushort_t* Ah = (const ushort_t*)Av;

  const int ABUFU = AF32 ? 8192 : 4096;    // ushorts per A buffer
  ushort_t* Ab[2] = { lds, lds + ABUFU };
  ushort_t* Bb[2] = { lds + 2 * ABUFU, lds + 2 * ABUFU + 4096 };

  // A staging: AF32 -> 2 frags/wave x 2 half-frags (16B = 4 floats per lane).
  // Half-frag region (fid,h): 512 ushorts at A_ + (fid*2+h)*512.
  auto stageA_f32 = [&](ushort_t* A_, int kt) {
    #pragma unroll
    for (int j = 0; j < 2; ++j) {
      const int fid = w * 2 + j;       // 0..7
      #pragma unroll
      for (int h = 0; h < 2; ++h) {
        const float* g = Xf + (size_t)(m0 + fid * 16 + lr) * CDIM +
                         kt + lk8 + h * 4;
        gl2lds16(g, &A_[(fid * 2 + h) * 512]);
      }
    }
  };
  auto stageA_bf16 = [&](ushort_t* A_, int kt) {
    #pragma unroll
    for (int j = 0; j < 2; ++j) {
      const int fid = w * 2 + j;
      const ushort_t* g = Ah + (size_t)(m0 + fid * 16 + lr) * CDIM + kt + lk8;
      gl2lds16(g, &A_[fid * 512]);
    }
  };
  auto stageB = [&](ushort_t* B_, int kt) {
    #pragma unroll
    for (int j = 0; j < 2; ++j) {
      const int fid = w * 2 + j;
      const size_t idx = (size_t)((n0 >> 4) + fid) * 16 + (kt >> 5);
      gl2lds16(Wpk + idx * 512 + lane * 8, &B_[fid * 512]);
    }
  };

  f32x4 acc[4][4];
  #pragma unroll
  for (int mf = 0; mf < 4; ++mf)
    #pragma unroll
    for (int nf = 0; nf < 4; ++nf)
      acc[mf][nf] = (f32x4){0.f, 0.f, 0.f, 0.f};

  auto compute = [&](const ushort_t* A_, const ushort_t* B_) {
    short8_t afr[4], bfr[4];
    #pragma unroll
    for (int nf = 0; nf < 4; ++nf)
      bfr[nf] = *(const short8_t*)&B_[((wn >> 4) + nf) * 512 + lane * 8];
    if (AF32) {
      const float* Afl = (const float*)A_;
      #pragma unroll
      for (int mf = 0; mf < 4; ++mf) {
        const int fid = (wm >> 4) + mf;
        const f32x4 lo = *(const f32x4*)&Afl[((fid * 2 + 0) * 64 + lane) * 4];
        const f32x4 hi = *(const f32x4*)&Afl[((fid * 2 + 1) * 64 + lane) * 4];
        afr[mf] = cvt8(lo, hi);
      }
    } else {
      #pragma unroll
      for (int mf = 0; mf < 4; ++mf)
        afr[mf] = *(const short8_t*)&A_[((wm >> 4) + mf) * 512 + lane * 8];
    }
    __builtin_amdgcn_s_setprio(1);
    #pragma unroll
    for (int mf = 0; mf < 4; ++mf)
      #pragma unroll
      for (int nf = 0; nf < 4; ++nf)
        acc[mf][nf] = __builtin_amdgcn_mfma_f32_16x16x32_bf16(
            afr[mf], bfr[nf], acc[mf][nf], 0, 0, 0);
    __builtin_amdgcn_s_setprio(0);
  };

  // ---- prologue: stage tile 0 (all DMA) ----
  if (AF32) stageA_f32(Ab[0], 0); else stageA_bf16(Ab[0], 0);
  stageB(Bb[0], 0);
  __builtin_amdgcn_sched_barrier(0);

  // ---- 16 K-steps: stage ks+1, counted wait, barrier, compute, barrier ----
#define KSTEP(ks, WN)                                                      \
  do {                                                                     \
    if ((ks) <= 14) {                                                      \
      if (AF32) stageA_f32(Ab[((ks) + 1) & 1], ((ks) + 1) * 32);           \
      else      stageA_bf16(Ab[((ks) + 1) & 1], ((ks) + 1) * 32);          \
      stageB(Bb[((ks) + 1) & 1], ((ks) + 1) * 32);                         \
    }                                                                      \
    __builtin_amdgcn_sched_barrier(0);                                     \
    WAIT_VM(WN);                                                           \
    __builtin_amdgcn_s_barrier();                                          \
    __builtin_amdgcn_sched_barrier(0);                                     \
    compute(Ab[(ks) & 1], Bb[(ks) & 1]);                                   \
    __builtin_amdgcn_s_barrier();                                          \
  } while (0)

  if (AF32) {
    // 6 DMA per step (4 A-half-frags + 2 B); newest 6 may stay in flight
    KSTEP(0, 6);  KSTEP(1, 6);  KSTEP(2, 6);  KSTEP(3, 6);
    KSTEP(4, 6);  KSTEP(5, 6);  KSTEP(6, 6);  KSTEP(7, 6);
    KSTEP(8, 6);  KSTEP(9, 6);  KSTEP(10, 6); KSTEP(11, 6);
    KSTEP(12, 6); KSTEP(13, 6); KSTEP(14, 6); KSTEP(15, 0);
  } else {
    KSTEP(0, 4);  KSTEP(1, 4);  KSTEP(2, 4);  KSTEP(3, 4);
    KSTEP(4, 4);  KSTEP(5, 4);  KSTEP(6, 4);  KSTEP(7, 4);
    KSTEP(8, 4);  KSTEP(9, 4);  KSTEP(10, 4); KSTEP(11, 4);
    KSTEP(12, 4); KSTEP(13, 4); KSTEP(14, 4); KSTEP(15, 0);
  }
#undef KSTEP

  // ---- epilogue ----
  if (OUTF32) {
    float* Yf = (float*)Yv;
    #pragma unroll
    for (int nf = 0; nf < 4; ++nf) {
      const int col = n0 + wn + nf * 16 + lr;
      const float bi = bias[col];
      #pragma unroll
      for (int mf = 0; mf < 4; ++mf) {
        #pragma unroll
        for (int r = 0; r < 4; ++r) {
          const int m = m0 + wm + mf * 16 + (lane >> 4) * 4 + r;
          __builtin_nontemporal_store(acc[mf][nf][r] + bi,
                                      &Yf[(size_t)m * CDIM + col]);
        }
      }
    }
  } else {
    // acc -> LDS [128][128] bf16 (32KB), then coalesced nt stores
    ushort_t* Yh = (ushort_t*)Yv;
    #pragma unroll
    for (int nf = 0; nf < 4; ++nf) {
      const int col = wn + nf * 16 + lr;
      const float bi = bias[n0 + col];
      #pragma unroll
      for (int mf = 0; mf < 4; ++mf) {
        #pragma unroll
        for (int r = 0; r < 4; ++r) {
          const int row = wm + mf * 16 + (lane >> 4) * 4 + r;
          float vv = acc[mf][nf][r] + bi;
          if (act) vv = (vv > 0.f) ? (vv + 1.f) : expf(vv);
          lds[row * 128 + col] = f2bf(vv);
        }
      }
    }
    __syncthreads();
    #pragma unroll
    for (int it = 0; it < 8; ++it) {
      const int u   = it * 256 + t;      // 16B packet, 0..2047
      const int row = u >> 4;
      const int c8  = (u & 15) * 8;
      const short8_t v = *(const short8_t*)&lds[u * 8];
      __builtin_nontemporal_store(
          v, (short8_t*)&Yh[(size_t)(m0 + row) * CDIM + n0 + c8]);
    }
  }
}

// Q/K/V projections fused, XCD-swizzled 1D grid (3072 blocks, r17-verified):
//   D -> xcd=D&7, n=(D>>3)&3, slot=D>>5, g=slot*8+xcd, m=g&255, z=g>>8.
__global__ __launch_bounds__(256)
void proj3_128(const float* __restrict__ Xq, const float* __restrict__ Xk,
               const float* __restrict__ Xv,
               const ushort_t* __restrict__ Wqp, const ushort_t* __restrict__ Wkp,
               const ushort_t* __restrict__ Wvp,
               const float* __restrict__ bq, const float* __restrict__ bk,
               const float* __restrict__ bv,
               ushort_t* __restrict__ Yq, ushort_t* __restrict__ Yk,
               ushort_t* __restrict__ Yv) {
  __shared__ __align__(16) ushort_t lds[24576];   // 48 KB (A fp32 dbuf + B dbuf)
  const int D    = blockIdx.x;        // 0..3071
  const int xcd  = D & 7;
  const int n    = (D >> 3) & 3;
  const int slot = D >> 5;            // 0..95
  const int g    = slot * 8 + xcd;    // 0..767
  const int m    = g & 255;
  const int z    = g >> 8;            // 0..2
  const float*    X    = (z == 0) ? Xq : (z == 1) ? Xk : Xv;
  const ushort_t* Wpk  = (z == 0) ? Wqp : (z == 1) ? Wkp : Wvp;
  const float*    bias = (z == 0) ? bq : (z == 1) ? bk : bv;
  ushort_t*       Y    = (z == 0) ? Yq : (z == 1) ? Yk : Yv;
  gemm128_body<1, 0>(X, Wpk, bias, Y, z < 2, m * 128, n * 128, lds);
}

// Output projection: bf16 A (DMA), fp32 out; same XCD swizzle (1024 blocks).
__global__ __launch_bounds__(256)
void outp_128(const ushort_t* __restrict__ A, const ushort_t* __restrict__ Wpk,
              const float* __restrict__ bias, float* __restrict__ Y) {
  __shared__ __align__(16) ushort_t lds[16384];
  const int D    = blockIdx.x;        // 0..1023
  const int xcd  = D & 7;
  const int n    = (D >> 3) & 3;
  const int slot = D >> 5;            // 0..31
  const int m    = slot * 8 + xcd;    // 0..255
  gemm128_body<0, 1>(A, Wpk, bias, Y, false, m * 128, n * 128, lds);
}

// ---------------------------------------------------------------------------
// kv GEMM (verified): per (b,h), kv[d][f] = sum_s k[s][d]*v[s][f], ksum via
// ones-MFMA. Split-K grid (32 bh, 16 chunks).
// ---------------------------------------------------------------------------
__global__ __launch_bounds__(256)
void gemm_kv(const ushort_t* __restrict__ Kb, const ushort_t* __restrict__ Vb,
             float* __restrict__ kvpart, float* __restrict__ ksumpart) {
  __shared__ __align__(16) ushort_t klds[8192];
  __shared__ __align__(16) ushort_t vlds[8192];
  const int bh    = blockIdx.x;
  const int chunk = blockIdx.y;
  const int b = bh >> 3, h = bh & 7;
  const int t = threadIdx.x;
  const int w = t >> 6;
  const int lane = t & 63;

  f32x4 acc[4];
  #pragma unroll
  for (int fg = 0; fg < 4; ++fg) acc[fg] = (f32x4){0.f, 0.f, 0.f, 0.f};
  f32x4 accs = (f32x4){0.f, 0.f, 0.f, 0.f};

  short8_t ones;
  #pragma unroll
  for (int i = 0; i < 8; ++i) ones[i] = (short)0x3F80;

  for (int round = 0; round < 4; ++round) {
    const int sbase = chunk * 512 + round * 128;
    __syncthreads();
    #pragma unroll
    for (int i = 0; i < 4; ++i) {
      const int idx  = i * 256 + t;
      const int sl   = idx >> 3;
      const int d8   = idx & 7;
      const size_t src = (size_t)((sbase + sl) * BATCH + b) * CDIM + h * DDIM + d8 * 8;
      const ushort8_t kp = *(const ushort8_t*)&Kb[src];
      const ushort8_t vp = *(const ushort8_t*)&Vb[src];
      const int sb  = sl >> 5;
      const int j   = sl & 7;
      const int lp0 = (d8 & 1) * 8 + ((sl >> 3) & 3) * 16;
      const int dg  = d8 >> 1;
      const int kbase = ((sb * 4 + dg) * 64 + lp0) * 8 + j;
      #pragma unroll
      for (int e = 0; e < 8; ++e) {
        klds[kbase + e * 8] = kp[e];
        vlds[kbase + e * 8] = vp[e];
      }
    }
    __syncthreads();
    #pragma unroll
    for (int sb = 0; sb < 4; ++sb) {
      const short8_t af = *(const short8_t*)&klds[((sb * 4 + w) * 64 + lane) * 8];
      accs = __builtin_amdgcn_mfma_f32_16x16x32_bf16(af, ones, accs, 0, 0, 0);
      #pragma unroll
      for (int fg = 0; fg < 4; ++fg) {
        const short8_t bf = *(const short8_t*)&vlds[((sb * 4 + fg) * 64 + lane) * 8];
        acc[fg] = __builtin_amdgcn_mfma_f32_16x16x32_bf16(af, bf, acc[fg], 0, 0, 0);
      }
    }
  }

  const size_t obase = ((size_t)bh * 16 + chunk) * 64;
  #pragma unroll
  for (int fg = 0; fg < 4; ++fg)
    #pragma unroll
    for (int r = 0; r < 4; ++r) {
      const int d = w * 16 + (lane >> 4) * 4 + r;
      kvpart[(obase + d) * 64 + fg * 16 + (lane & 15)] = acc[fg][r];
    }
  if ((lane & 15) == 0) {
    #pragma unroll
    for (int r = 0; r < 4; ++r)
      ksumpart[obase + w * 16 + (lane >> 4) * 4 + r] = accs[r];
  }
}

// ---------------------------------------------------------------------------
__global__ __launch_bounds__(256)
void kv_finish(const float* __restrict__ kvpart, const float* __restrict__ ksumpart,
               ushort_t* __restrict__ kvT) {
  const int bh = blockIdx.x;
  const int t  = threadIdx.x;
  for (int idx = t; idx < 4096; idx += 256) {
    const int d = idx >> 6, f = idx & 63;
    float s = 0.f;
    for (int c = 0; c < 16; ++c)
      s += kvpart[(((size_t)bh * 16 + c) * 64 + d) * 64 + f];
    kvT[((size_t)bh * 80 + f) * 64 + d] = f2bf(s);
  }
  if (t < 64) {
    float s = 0.f;
    for (int c = 0; c < 16; ++c)
      s += ksumpart[((size_t)bh * 16 + c) * 64 + t];
    kvT[((size_t)bh * 80 + 64) * 64 + t] = f2bf(s);
  }
  for (int i = t; i < 15 * 64; i += 256)
    kvT[((size_t)bh * 80 + 65) * 64 + i] = 0;
}

// ---------------------------------------------------------------------------
// qkv GEMM (verified): y = (q @ kv) / (q . ksum + eps)
// ---------------------------------------------------------------------------
__global__ __launch_bounds__(256)
void gemm_qkv(ushort_t* __restrict__ Qb, const ushort_t* __restrict__ kvT) {
  __shared__ __align__(16) ushort_t alds[8192];
  __shared__ __align__(16) ushort_t blds[5120];
  const int bh    = blockIdx.x;
  const int chunk = blockIdx.y;
  const int b = bh >> 3, h = bh & 7;
  const int t = threadIdx.x;
  const int w = t >> 6;
  const int lane = t & 63;
  const int lr = lane & 15;
  const int lk = (lane >> 4) * 8;

  #pragma unroll
  for (int i = 0; i < 4; ++i) {
    const int fidx = w * 4 + i;
    const int ks = fidx >> 3, fm = fidx & 7;
    const ushort_t* src = Qb +
        (size_t)((chunk * 128 + fm * 16 + lr) * BATCH + b) * CDIM +
        h * DDIM + ks * 32 + lk;
    gl2lds16(src, &alds[fidx * 512]);
  }
  for (int idx = w; idx < 10; idx += 4) {
    const int ks = idx / 5, fg = idx % 5;
    const ushort_t* src = kvT + (size_t)(bh * 80 + fg * 16 + lr) * 64 + ks * 32 + lk;
    gl2lds16(src, &blds[idx * 512]);
  }
  __syncthreads();

  f32x4 acc[2][5];
  #pragma unroll
  for (int mi = 0; mi < 2; ++mi)
    #pragma unroll
    for (int fg = 0; fg < 5; ++fg)
      acc[mi][fg] = (f32x4){0.f, 0.f, 0.f, 0.f};

  #pragma unroll
  for (int ks = 0; ks < 2; ++ks) {
    short8_t af[2], bf[5];
    #pragma unroll
    for (int mi = 0; mi < 2; ++mi)
      af[mi] = *(const short8_t*)&alds[(ks * 8 + w * 2 + mi) * 512 + lane * 8];
    #pragma unroll
    for (int fg = 0; fg < 5; ++fg)
      bf[fg] = *(const short8_t*)&blds[(ks * 5 + fg) * 512 + lane * 8];
    #pragma unroll
    for (int mi = 0; mi < 2; ++mi)
      #pragma unroll
      for (int fg = 0; fg < 5; ++fg)
        acc[mi][fg] = __builtin_amdgcn_mfma_f32_16x16x32_bf16(
            af[mi], bf[fg], acc[mi][fg], 0, 0, 0);
  }

  #pragma unroll
  for (int mi = 0; mi < 2; ++mi) {
    #pragma unroll
    for (int r = 0; r < 4; ++r) {
      const float dv  = __shfl(acc[mi][4][r], lane & 48);
      const float inv = 1.f / (dv + EPS_F);
      const int s = chunk * 128 + w * 32 + mi * 16 + (lane >> 4) * 4 + r;
      const size_t rowb = (size_t)(s * BATCH + b) * CDIM + h * DDIM;
      #pragma unroll
      for (int fg = 0; fg < 4; ++fg)
        Qb[rowb + fg * 16 + lr] = f2bf(acc[mi][fg][r] * inv);
    }
  }
}

// ---------------------------------------------------------------------------
extern "C" void kernel_launch(void* const* d_in, const int* in_sizes, int n_in,
                              void* d_out, int out_size, void* d_ws, size_t ws_size,
                              hipStream_t stream) {
  const float* q_in = (const float*)d_in[0];
  const float* k_in = (const float*)d_in[1];
  const float* v_in = (const float*)d_in[2];
  const float* Wq   = (const float*)d_in[3];
  const float* bq   = (const float*)d_in[4];
  const float* Wk   = (const float*)d_in[5];
  const float* bk   = (const float*)d_in[6];
  const float* Wv   = (const float*)d_in[7];
  const float* bv   = (const float*)d_in[8];
  const float* Wp   = (const float*)d_in[9];
  const float* bp   = (const float*)d_in[10];
  float* out = (float*)d_out;

  const size_t NTOK = (size_t)MROWS * CDIM;      // 16,777,216 elems
  const size_t NW   = (size_t)CDIM * CDIM;       // 262,144
  ushort_t* Wqp    = (ushort_t*)d_ws;            // fragment-packed bf16 weights
  ushort_t* Wkp    = Wqp + NW;
  ushort_t* Wvp    = Wkp + NW;
  ushort_t* Wpp    = Wvp + NW;
  ushort_t* qbuf   = Wpp + NW;
  ushort_t* kbuf   = qbuf + NTOK;
  ushort_t* vbuf   = kbuf + NTOK;
  ushort_t* kvT    = vbuf + NTOK;                           // 32*80*64
  float* kvpart    = (float*)(kvT + (size_t)32 * 80 * 64);  // 512*64*64
  float* ksumpart  = kvpart + (size_t)512 * 64 * 64;        // 512*64

  const dim3 blk(256);

  // 1) Weights fp32 -> bf16, fragment-packed
  cvtW_pack<<<dim3(128, 4), blk, 0, stream>>>(Wq, Wk, Wv, Wp,
                                              Wqp, Wkp, Wvp, Wpp);

  // 2) Q/K/V projections: all-DMA staging (A fp32 in LDS, cvt post-ds_read),
  //    XCD-swizzled grid
  proj3_128<<<dim3(3072), blk, 0, stream>>>(
      q_in, k_in, v_in, Wqp, Wkp, Wvp, bq, bk, bv, qbuf, kbuf, vbuf);

  // 3) kv = sum_s k^T v (+ ksum via ones-MFMA), split-K then finish
  gemm_kv<<<dim3(32, 16), blk, 0, stream>>>(kbuf, vbuf, kvpart, ksumpart);
  kv_finish<<<dim3(32), blk, 0, stream>>>(kvpart, ksumpart, kvT);

  // 4) y = (q @ kv) / (q . ksum + eps), bf16 in place over q buffer
  gemm_qkv<<<dim3(32, 64), blk, 0, stream>>>(qbuf, kvT);

  // 5) Output projection: 128^2-tile, XCD-swizzled, bf16 A -> fp32 d_out
  outp_128<<<dim3(1024), blk, 0, stream>>>(qbuf, Wpp, bp, out);
}